// Round 1
// baseline (159.833 us; speedup 1.0000x reference)
//
#include <hip/hip_runtime.h>

#define S_LEN 1024
#define D_TOT 512
#define D_E   448
#define D_H   64

__device__ __forceinline__ float wave_sum64(float v) {
#pragma unroll
  for (int o = 32; o > 0; o >>= 1) v += __shfl_xor(v, o);
  return v;
}

// ---------------- NT GEMM body: C[m,n] = sum_k A[m,k]*B[n,k] + bias[n]
// A: M x K (lda = K), B: N x K (ldb = K). BM=BN=64, BK=16, 256 thr, 4x4/thread.
__device__ __forceinline__ void gemm_nt_body(
    const float* __restrict__ A, const float* __restrict__ B,
    const float* __restrict__ bias, float* __restrict__ C,
    int K, int ldc, int mBase, int nBase)
{
  __shared__ float As[16][68];
  __shared__ float Bs[16][68];
  const int t   = threadIdx.x;
  const int tm  = t & 15, tn = t >> 4;
  const int lrow = t >> 2, lk4 = (t & 3) << 2;
  float acc[4][4] = {};
  for (int k0 = 0; k0 < K; k0 += 16) {
    float4 av = *(const float4*)(A + (size_t)(mBase + lrow) * K + k0 + lk4);
    float4 bv = *(const float4*)(B + (size_t)(nBase + lrow) * K + k0 + lk4);
    __syncthreads();
    As[lk4+0][lrow]=av.x; As[lk4+1][lrow]=av.y; As[lk4+2][lrow]=av.z; As[lk4+3][lrow]=av.w;
    Bs[lk4+0][lrow]=bv.x; Bs[lk4+1][lrow]=bv.y; Bs[lk4+2][lrow]=bv.z; Bs[lk4+3][lrow]=bv.w;
    __syncthreads();
#pragma unroll
    for (int kk = 0; kk < 16; ++kk) {
      float a4[4], b4[4];
      *(float4*)a4 = *(const float4*)&As[kk][tm << 2];
      *(float4*)b4 = *(const float4*)&Bs[kk][tn << 2];
#pragma unroll
      for (int i = 0; i < 4; ++i)
#pragma unroll
        for (int j = 0; j < 4; ++j) acc[i][j] = fmaf(a4[i], b4[j], acc[i][j]);
    }
  }
#pragma unroll
  for (int i = 0; i < 4; ++i) {
    int m = mBase + (tm << 2) + i;
#pragma unroll
    for (int j = 0; j < 4; ++j) {
      int n = nBase + (tn << 2) + j;
      C[(size_t)m * ldc + n] = acc[i][j] + bias[n];
    }
  }
}

__global__ __launch_bounds__(256) void qkv_kernel(
    const float* __restrict__ x,
    const float* __restrict__ wq, const float* __restrict__ bq,
    const float* __restrict__ wk, const float* __restrict__ bk,
    const float* __restrict__ wv, const float* __restrict__ bv,
    float* __restrict__ q, float* __restrict__ k, float* __restrict__ v)
{
  const float* W; const float* b; float* o;
  if (blockIdx.z == 0)      { W = wq; b = bq; o = q; }
  else if (blockIdx.z == 1) { W = wk; b = bk; o = k; }
  else                      { W = wv; b = bv; o = v; }
  gemm_nt_body(x, W, b, o, D_TOT, D_TOT, blockIdx.y << 6, blockIdx.x << 6);
}

__global__ __launch_bounds__(256) void final_kernel(
    const float* __restrict__ A, const float* __restrict__ wo,
    const float* __restrict__ bo, float* __restrict__ out)
{
  gemm_nt_body(A, wo, bo, out, D_TOT, D_TOT, blockIdx.y << 6, blockIdx.x << 6);
}

// ---------------- per-row stats: qn = |qe|^2 ; u = project(exp0(qh)); u2 = |u|^2
__global__ __launch_bounds__(64) void stats_kernel(
    const float* __restrict__ q, const float* __restrict__ k,
    float* __restrict__ qn, float* __restrict__ kn,
    float* __restrict__ uh, float* __restrict__ vh,
    float* __restrict__ uh2, float* __restrict__ vh2)
{
  const int r = blockIdx.x;
  const int side = blockIdx.y;
  const int lane = threadIdx.x;
  const float* src = (side ? k : q) + (size_t)r * D_TOT;

  float ss = 0.f;
#pragma unroll
  for (int j = 0; j < 7; ++j) {
    float xv = src[lane + 64 * j];
    ss = fmaf(xv, xv, ss);
  }
  ss = wave_sum64(ss);

  float h  = src[D_E + lane];
  float n2 = wave_sum64(h * h);
  float n  = fmaxf(sqrtf(n2), 1e-5f);
  float th = tanhf(n);
  float pre = th * h / n;
  float pn2 = wave_sum64(pre * pre);
  float pn  = fmaxf(sqrtf(pn2), 1e-5f);
  float scale = fminf(0.999f / pn, 1.f);
  float u  = pre * scale;
  float u2 = wave_sum64(u * u);

  float* dn  = side ? kn  : qn;
  float* du  = side ? vh  : uh;
  float* du2 = side ? vh2 : uh2;
  du[(size_t)r * 64 + lane] = u;
  if (lane == 0) { dn[r] = ss; du2[r] = u2; }
}

// ---------------- scores: E = exp(clip(-(d_e + alpha*d_h^2)/sqrt(512), -50, 0))
__global__ __launch_bounds__(256) void score_kernel(
    const float* __restrict__ q, const float* __restrict__ k,
    const float* __restrict__ uh, const float* __restrict__ vh,
    const float* __restrict__ qn, const float* __restrict__ kn,
    const float* __restrict__ uh2, const float* __restrict__ vh2,
    const float* __restrict__ alpha_u,
    float* __restrict__ E, float* __restrict__ rowpart)
{
  __shared__ float As[16][68];
  __shared__ float Bs[16][68];
  __shared__ float red[64][17];
  const int t   = threadIdx.x;
  const int tm  = t & 15, tn = t >> 4;
  const int lrow = t >> 2, lk4 = (t & 3) << 2;
  const int mBase = blockIdx.y << 6, nBase = blockIdx.x << 6;
  float accE[4][4] = {};
  float accH[4][4] = {};
  for (int kt = 0; kt < 32; ++kt) {
    const int k0 = kt << 4;
    const float* Ap; const float* Bp; int ld;
    if (k0 < D_E) { Ap = q + k0;           Bp = k + k0;           ld = D_TOT; }
    else          { Ap = uh + (k0 - D_E);  Bp = vh + (k0 - D_E);  ld = D_H;   }
    float4 av = *(const float4*)(Ap + (size_t)(mBase + lrow) * ld + lk4);
    float4 bv = *(const float4*)(Bp + (size_t)(nBase + lrow) * ld + lk4);
    __syncthreads();
    As[lk4+0][lrow]=av.x; As[lk4+1][lrow]=av.y; As[lk4+2][lrow]=av.z; As[lk4+3][lrow]=av.w;
    Bs[lk4+0][lrow]=bv.x; Bs[lk4+1][lrow]=bv.y; Bs[lk4+2][lrow]=bv.z; Bs[lk4+3][lrow]=bv.w;
    __syncthreads();
    if (k0 < D_E) {
#pragma unroll
      for (int kk = 0; kk < 16; ++kk) {
        float a4[4], b4[4];
        *(float4*)a4 = *(const float4*)&As[kk][tm << 2];
        *(float4*)b4 = *(const float4*)&Bs[kk][tn << 2];
#pragma unroll
        for (int i = 0; i < 4; ++i)
#pragma unroll
          for (int j = 0; j < 4; ++j) accE[i][j] = fmaf(a4[i], b4[j], accE[i][j]);
      }
    } else {
#pragma unroll
      for (int kk = 0; kk < 16; ++kk) {
        float a4[4], b4[4];
        *(float4*)a4 = *(const float4*)&As[kk][tm << 2];
        *(float4*)b4 = *(const float4*)&Bs[kk][tn << 2];
#pragma unroll
        for (int i = 0; i < 4; ++i)
#pragma unroll
          for (int j = 0; j < 4; ++j) accH[i][j] = fmaf(a4[i], b4[j], accH[i][j]);
      }
    }
  }

  const float alpha = log1pf(expf(alpha_u[0]));
  const float inv_s = 0.04419417382415922f;   // 1/sqrt(512)
#pragma unroll
  for (int i = 0; i < 4; ++i) {
    const int s = mBase + (tm << 2) + i;
    const float qns = qn[s], u2 = uh2[s];
    float rs = 0.f;
#pragma unroll
    for (int j = 0; j < 4; ++j) {
      const int tt = nBase + (tn << 2) + j;
      float de  = qns + kn[tt] - 2.f * accE[i][j];
      float dot = accH[i][j];
      float v2  = vh2[tt];
      float Ac  = 1.f - 2.f * dot + v2;
      float Bc  = 1.f - u2;
      float num2 = Ac*Ac*u2 + Bc*Bc*v2 - 2.f*Ac*Bc*dot;
      float den  = fmaxf(1.f - 2.f*dot + u2*v2, 1e-5f);
      float frac = sqrtf(fmaxf(num2, 0.f)) / den;
      float nrm  = fminf(frac, 0.999f);
      float dh   = 2.f * atanhf(nrm);
      float dist = de + alpha * dh * dh;
      float lg   = fminf(fmaxf(-dist * inv_s, -50.f), 0.f);
      float e    = expf(lg);
      E[(size_t)s * S_LEN + tt] = e;
      rs += e;
    }
    red[(tm << 2) + i][tn] = rs;
  }
  __syncthreads();
  if (t < 64) {
    float sum = 0.f;
#pragma unroll
    for (int c = 0; c < 16; ++c) sum += red[t][c];
    rowpart[(size_t)(mBase + t) * 16 + blockIdx.x] = sum;
  }
}

__global__ __launch_bounds__(256) void rowsum_kernel(
    const float* __restrict__ rowpart, float* __restrict__ rinv)
{
  int s = blockIdx.x * 256 + threadIdx.x;
  if (s < S_LEN) {
    float sum = 0.f;
#pragma unroll
    for (int c = 0; c < 16; ++c) sum += rowpart[s * 16 + c];
    rinv[s] = 1.f / sum;
  }
}

// ---------------- attn @ V (NN): out1[s,d] = rinv[s] * sum_t E[s,t]*v[t,d]
__global__ __launch_bounds__(256) void av_kernel(
    const float* __restrict__ E, const float* __restrict__ v,
    const float* __restrict__ rinv, float* __restrict__ out1)
{
  __shared__ float As[16][68];   // As[kk][m]
  __shared__ float Bs[16][68];   // Bs[kk][n]
  const int t   = threadIdx.x;
  const int tm  = t & 15, tn = t >> 4;
  const int lrow = t >> 2, lk4 = (t & 3) << 2;   // A loads
  const int bkr  = t >> 4, bn4 = (t & 15) << 2;  // B loads
  const int mBase = blockIdx.y << 6, nBase = blockIdx.x << 6;
  float acc[4][4] = {};
  for (int k0 = 0; k0 < S_LEN; k0 += 16) {
    float4 av = *(const float4*)(E + (size_t)(mBase + lrow) * S_LEN + k0 + lk4);
    float4 bv = *(const float4*)(v + (size_t)(k0 + bkr) * D_TOT + nBase + bn4);
    __syncthreads();
    As[lk4+0][lrow]=av.x; As[lk4+1][lrow]=av.y; As[lk4+2][lrow]=av.z; As[lk4+3][lrow]=av.w;
    *(float4*)&Bs[bkr][bn4] = bv;
    __syncthreads();
#pragma unroll
    for (int kk = 0; kk < 16; ++kk) {
      float a4[4], b4[4];
      *(float4*)a4 = *(const float4*)&As[kk][tm << 2];
      *(float4*)b4 = *(const float4*)&Bs[kk][tn << 2];
#pragma unroll
      for (int i = 0; i < 4; ++i)
#pragma unroll
        for (int j = 0; j < 4; ++j) acc[i][j] = fmaf(a4[i], b4[j], acc[i][j]);
    }
  }
#pragma unroll
  for (int i = 0; i < 4; ++i) {
    const int m = mBase + (tm << 2) + i;
    const float sc = rinv[m];
#pragma unroll
    for (int j = 0; j < 4; ++j) {
      const int n = nBase + (tn << 2) + j;
      out1[(size_t)m * D_TOT + n] = acc[i][j] * sc;
    }
  }
}

extern "C" void kernel_launch(void* const* d_in, const int* in_sizes, int n_in,
                              void* d_out, int out_size, void* d_ws, size_t ws_size,
                              hipStream_t stream)
{
  const float* x   = (const float*)d_in[0];
  const float* wq  = (const float*)d_in[1];
  const float* bq  = (const float*)d_in[2];
  const float* wk  = (const float*)d_in[3];
  const float* bk  = (const float*)d_in[4];
  const float* wv  = (const float*)d_in[5];
  const float* bv  = (const float*)d_in[6];
  const float* wo  = (const float*)d_in[7];
  const float* bo  = (const float*)d_in[8];
  const float* alpha_u = (const float*)d_in[9];
  float* out = (float*)d_out;

  float* ws      = (float*)d_ws;
  float* q       = ws;                  // 1024*512
  float* k       = q    + 524288;
  float* v       = k    + 524288;
  float* uh      = v    + 524288;       // 1024*64
  float* vh      = uh   + 65536;
  float* qn      = vh   + 65536;        // 1024
  float* kn      = qn   + 1024;
  float* uh2     = kn   + 1024;
  float* vh2     = uh2  + 1024;
  float* rinv    = vh2  + 1024;
  float* rowpart = rinv + 1024;         // 1024*16
  float* E       = rowpart + 16384;     // 1024*1024
  float* out1    = E    + 1048576;      // 1024*512

  qkv_kernel<<<dim3(8, 16, 3), 256, 0, stream>>>(x, wq, bq, wk, bk, wv, bv, q, k, v);
  stats_kernel<<<dim3(1024, 2), 64, 0, stream>>>(q, k, qn, kn, uh, vh, uh2, vh2);
  score_kernel<<<dim3(16, 16), 256, 0, stream>>>(q, k, uh, vh, qn, kn, uh2, vh2,
                                                 alpha_u, E, rowpart);
  rowsum_kernel<<<dim3(4), 256, 0, stream>>>(rowpart, rinv);
  av_kernel<<<dim3(8, 16), 256, 0, stream>>>(E, v, rinv, out1);
  final_kernel<<<dim3(8, 16), 256, 0, stream>>>(out1, wo, bo, out);
}

// Round 2
// 69.667 us; speedup vs baseline: 2.2942x; 2.2942x over previous
//
#include <hip/hip_runtime.h>

#define S_LEN 1024
#define D_TOT 512
#define D_E   448
#define D_H   64

typedef short bf16x8 __attribute__((ext_vector_type(8)));
typedef float f32x4  __attribute__((ext_vector_type(4)));

__device__ __forceinline__ float wave_sum64(float v) {
#pragma unroll
  for (int o = 32; o > 0; o >>= 1) v += __shfl_xor(v, o);
  return v;
}

// split fp32 into bf16 hi (RNE) + bf16 lo (RNE of remainder)
__device__ __forceinline__ void bsplit(float f, unsigned short &h, unsigned short &l) {
  unsigned u  = __builtin_bit_cast(unsigned, f);
  unsigned ur = u + 0x7fffu + ((u >> 16) & 1u);
  h = (unsigned short)(ur >> 16);
  float fh = __builtin_bit_cast(float, ur & 0xffff0000u);
  float r  = f - fh;
  unsigned u2 = __builtin_bit_cast(unsigned, r);
  l = (unsigned short)((u2 + 0x7fffu + ((u2 >> 16) & 1u)) >> 16);
}

// ---------------- shared MFMA NT-GEMM core ----------------
// C[m,n] = sum_k (Ah+Al)[m,k] * (Bh+Bl)[n,k]   (hi/lo split, 3 MFMAs per frag)
// block 64x64, 4 waves as 2x2 of 32x32, BK=32, LDS tiles [64][40] (pad -> 2-way)
#define DO_MFMA(ACC)                                                                   \
  _Pragma("unroll") for (int i = 0; i < 2; ++i)                                        \
  _Pragma("unroll") for (int j = 0; j < 2; ++j) {                                      \
    ACC[i][j] = __builtin_amdgcn_mfma_f32_16x16x32_bf16(fAh[i], fBh[j], ACC[i][j], 0, 0, 0); \
    ACC[i][j] = __builtin_amdgcn_mfma_f32_16x16x32_bf16(fAh[i], fBl[j], ACC[i][j], 0, 0, 0); \
    ACC[i][j] = __builtin_amdgcn_mfma_f32_16x16x32_bf16(fAl[i], fBh[j], ACC[i][j], 0, 0, 0); \
  }

template<int NSTEPS, int ESTEPS>
__device__ __forceinline__ void mfma_core(
    const unsigned short* __restrict__ Ah, const unsigned short* __restrict__ Al, int lda,
    const unsigned short* __restrict__ Bh, const unsigned short* __restrict__ Bl, int ldb,
    int mBase, int nBase, unsigned short* lds,
    f32x4 (&accE)[2][2], f32x4 (&accH)[2][2])
{
  const int t    = threadIdx.x;
  const int lane = t & 63;
  const int wave = t >> 6;
  const int wr   = wave >> 1, wc = wave & 1;
  const int srow = t >> 2, scol = (t & 3) << 3;
  unsigned short* LAh = lds;
  unsigned short* LAl = lds + 2560;
  unsigned short* LBh = lds + 5120;
  unsigned short* LBl = lds + 7680;
  const size_t aoff = (size_t)(mBase + srow) * lda + scol;
  const size_t boff = (size_t)(nBase + srow) * ldb + scol;
  uint4 rah = *(const uint4*)(Ah + aoff);
  uint4 ral = *(const uint4*)(Al + aoff);
  uint4 rbh = *(const uint4*)(Bh + boff);
  uint4 rbl = *(const uint4*)(Bl + boff);
  const int woff  = srow * 40 + scol;
  const int frow  = lane & 15;
  const int fk    = (lane >> 4) << 3;
  const int raoff = (wr * 32 + frow) * 40 + fk;
  const int rboff = (wc * 32 + frow) * 40 + fk;
#pragma unroll
  for (int s = 0; s < NSTEPS; ++s) {
    __syncthreads();
    *(uint4*)(LAh + woff) = rah;
    *(uint4*)(LAl + woff) = ral;
    *(uint4*)(LBh + woff) = rbh;
    *(uint4*)(LBl + woff) = rbl;
    if (s + 1 < NSTEPS) {
      const size_t o = (size_t)(s + 1) * 32;
      rah = *(const uint4*)(Ah + aoff + o);
      ral = *(const uint4*)(Al + aoff + o);
      rbh = *(const uint4*)(Bh + boff + o);
      rbl = *(const uint4*)(Bl + boff + o);
    }
    __syncthreads();
    bf16x8 fAh[2], fAl[2], fBh[2], fBl[2];
#pragma unroll
    for (int i = 0; i < 2; ++i) {
      fAh[i] = *(const bf16x8*)(LAh + raoff + i * 640);
      fAl[i] = *(const bf16x8*)(LAl + raoff + i * 640);
      fBh[i] = *(const bf16x8*)(LBh + rboff + i * 640);
      fBl[i] = *(const bf16x8*)(LBl + rboff + i * 640);
    }
    if (s < ESTEPS) { DO_MFMA(accE) } else { DO_MFMA(accH) }
  }
}

// ---------------- convert inputs to hi/lo bf16 ----------------
__global__ __launch_bounds__(256) void convert_kernel(
    const float* __restrict__ x,  const float* __restrict__ wq,
    const float* __restrict__ wk, const float* __restrict__ wv,
    const float* __restrict__ wo,
    unsigned short* __restrict__ xh,  unsigned short* __restrict__ xl,
    unsigned short* __restrict__ wqh, unsigned short* __restrict__ wql,
    unsigned short* __restrict__ wkh, unsigned short* __restrict__ wkl,
    unsigned short* __restrict__ wvh, unsigned short* __restrict__ wvl,
    unsigned short* __restrict__ woh, unsigned short* __restrict__ wol)
{
  int i = (blockIdx.x * 256 + threadIdx.x) * 4;
  const float* src; unsigned short *dh, *dl; int off;
  if      (i <  524288) { src = x;  dh = xh;  dl = xl;  off = i; }
  else if (i <  786432) { src = wq; dh = wqh; dl = wql; off = i -  524288; }
  else if (i < 1048576) { src = wk; dh = wkh; dl = wkl; off = i -  786432; }
  else if (i < 1310720) { src = wv; dh = wvh; dl = wvl; off = i - 1048576; }
  else                  { src = wo; dh = woh; dl = wol; off = i - 1310720; }
  float4 v = *(const float4*)(src + off);
  ushort4 h4, l4;
  bsplit(v.x, h4.x, l4.x); bsplit(v.y, h4.y, l4.y);
  bsplit(v.z, h4.z, l4.z); bsplit(v.w, h4.w, l4.w);
  *(ushort4*)(dh + off) = h4;
  *(ushort4*)(dl + off) = l4;
}

// ---------------- QKV GEMMs ----------------
__global__ __launch_bounds__(256) void qkv_mfma(
    const unsigned short* __restrict__ xh,  const unsigned short* __restrict__ xl,
    const unsigned short* __restrict__ wqh, const unsigned short* __restrict__ wql,
    const unsigned short* __restrict__ wkh, const unsigned short* __restrict__ wkl,
    const unsigned short* __restrict__ wvh, const unsigned short* __restrict__ wvl,
    const float* __restrict__ bq, const float* __restrict__ bk, const float* __restrict__ bv,
    unsigned short* __restrict__ Qch, unsigned short* __restrict__ Qcl,
    unsigned short* __restrict__ Kch, unsigned short* __restrict__ Kcl,
    unsigned short* __restrict__ vTh, unsigned short* __restrict__ vTl,
    float* __restrict__ qh_f, float* __restrict__ kh_f,
    float* __restrict__ qnpart, float* __restrict__ knpart)
{
  __shared__ unsigned short lds[10240];
  const int z = blockIdx.z;
  const unsigned short *Bh_, *Bl_; const float* bias;
  if (z == 0)      { Bh_ = wqh; Bl_ = wql; bias = bq; }
  else if (z == 1) { Bh_ = wkh; Bl_ = wkl; bias = bk; }
  else             { Bh_ = wvh; Bl_ = wvl; bias = bv; }
  const int mBase = blockIdx.y << 6, nBase = blockIdx.x << 6;
  f32x4 zero = {0.f, 0.f, 0.f, 0.f};
  f32x4 accE[2][2] = {{zero, zero}, {zero, zero}};
  f32x4 accH[2][2] = {{zero, zero}, {zero, zero}};
  mfma_core<16, 16>(xh, xl, D_TOT, Bh_, Bl_, D_TOT, mBase, nBase, lds, accE, accH);

  const int lane = threadIdx.x & 63, wave = threadIdx.x >> 6;
  const int wr = wave >> 1, wc = wave & 1;
  const int r4 = (lane >> 4) << 2, cn = lane & 15;
  int   nj[2]; float bj[2];
#pragma unroll
  for (int j = 0; j < 2; ++j) { nj[j] = nBase + wc * 32 + j * 16 + cn; bj[j] = bias[nj[j]]; }

  if (z == 2) {
#pragma unroll
    for (int i = 0; i < 2; ++i)
#pragma unroll
      for (int j = 0; j < 2; ++j) {
        const int s0 = mBase + wr * 32 + i * 16 + r4;
        ushort4 h4, l4;
        float v0 = accE[i][j][0] + bj[j]; bsplit(v0, h4.x, l4.x);
        float v1 = accE[i][j][1] + bj[j]; bsplit(v1, h4.y, l4.y);
        float v2 = accE[i][j][2] + bj[j]; bsplit(v2, h4.z, l4.z);
        float v3 = accE[i][j][3] + bj[j]; bsplit(v3, h4.w, l4.w);
        *(ushort4*)(vTh + (size_t)nj[j] * S_LEN + s0) = h4;
        *(ushort4*)(vTl + (size_t)nj[j] * S_LEN + s0) = l4;
      }
  } else {
    unsigned short* Ch = z ? Kch : Qch;
    unsigned short* Cl = z ? Kcl : Qcl;
    float* hf  = z ? kh_f : qh_f;
    float* np_ = z ? knpart : qnpart;
    if (nBase < D_E) {
#pragma unroll
      for (int i = 0; i < 2; ++i) {
        float pp[4] = {0.f, 0.f, 0.f, 0.f};
#pragma unroll
        for (int j = 0; j < 2; ++j)
#pragma unroll
          for (int r = 0; r < 4; ++r) {
            const int s = mBase + wr * 32 + i * 16 + r4 + r;
            float val = accE[i][j][r] + bj[j];
            unsigned short h, l; bsplit(val, h, l);
            Ch[(size_t)s * D_TOT + nj[j]] = h;
            Cl[(size_t)s * D_TOT + nj[j]] = l;
            pp[r] = fmaf(val, val, pp[r]);
          }
#pragma unroll
        for (int r = 0; r < 4; ++r) {
          float p = pp[r];
#pragma unroll
          for (int o = 1; o < 16; o <<= 1) p += __shfl_xor(p, o);
          if (cn == 0) {
            const int s = mBase + wr * 32 + i * 16 + r4 + r;
            np_[(size_t)s * 16 + (nBase >> 6) * 2 + wc] = p;
          }
        }
      }
    } else {
#pragma unroll
      for (int i = 0; i < 2; ++i)
#pragma unroll
        for (int j = 0; j < 2; ++j)
#pragma unroll
          for (int r = 0; r < 4; ++r) {
            const int s = mBase + wr * 32 + i * 16 + r4 + r;
            hf[(size_t)s * 64 + (nj[j] - D_E)] = accE[i][j][r] + bj[j];
          }
    }
  }
}

// ---------------- per-row hyperbolic stats ----------------
__global__ __launch_bounds__(64) void stats_kernel(
    const float* __restrict__ qh_f, const float* __restrict__ kh_f,
    const float* __restrict__ qnpart, const float* __restrict__ knpart,
    unsigned short* __restrict__ Qch, unsigned short* __restrict__ Qcl,
    unsigned short* __restrict__ Kch, unsigned short* __restrict__ Kcl,
    float* __restrict__ qn, float* __restrict__ kn,
    float* __restrict__ uh2, float* __restrict__ vh2)
{
  const int r = blockIdx.x, side = blockIdx.y, lane = threadIdx.x;
  const float* hf    = side ? kh_f : qh_f;
  const float* npart = side ? knpart : qnpart;
  float ssum = 0.f;
#pragma unroll
  for (int c = 0; c < 14; ++c) ssum += npart[(size_t)r * 16 + c];

  float h  = hf[(size_t)r * 64 + lane];
  float n2 = wave_sum64(h * h);
  float n  = fmaxf(sqrtf(n2), 1e-5f);
  float th = tanhf(n);
  float pre = th * h / n;
  float pn2 = wave_sum64(pre * pre);
  float pn  = fmaxf(sqrtf(pn2), 1e-5f);
  float scale = fminf(0.999f / pn, 1.f);
  float u  = pre * scale;
  float u2 = wave_sum64(u * u);

  unsigned short hh, ll; bsplit(u, hh, ll);
  (side ? Kch : Qch)[(size_t)r * D_TOT + D_E + lane] = hh;
  (side ? Kcl : Qcl)[(size_t)r * D_TOT + D_E + lane] = ll;
  if (lane == 0) {
    (side ? kn : qn)[r]   = ssum;
    (side ? vh2 : uh2)[r] = u2;
  }
}

// ---------------- fused score GEMM + transcendental epilogue ----------------
__global__ __launch_bounds__(256) void score_mfma(
    const unsigned short* __restrict__ Qch, const unsigned short* __restrict__ Qcl,
    const unsigned short* __restrict__ Kch, const unsigned short* __restrict__ Kcl,
    const float* __restrict__ qn, const float* __restrict__ kn,
    const float* __restrict__ uh2, const float* __restrict__ vh2,
    const float* __restrict__ alpha_u,
    unsigned short* __restrict__ Eh, unsigned short* __restrict__ El,
    float* __restrict__ rowpart)
{
  __shared__ unsigned short lds[10240];
  const int mBase = blockIdx.y << 6, nBase = blockIdx.x << 6;
  f32x4 zero = {0.f, 0.f, 0.f, 0.f};
  f32x4 accE[2][2] = {{zero, zero}, {zero, zero}};
  f32x4 accH[2][2] = {{zero, zero}, {zero, zero}};
  mfma_core<16, 14>(Qch, Qcl, D_TOT, Kch, Kcl, D_TOT, mBase, nBase, lds, accE, accH);

  const int lane = threadIdx.x & 63, wave = threadIdx.x >> 6;
  const int wr = wave >> 1, wc = wave & 1;
  const int r4 = (lane >> 4) << 2, cn = lane & 15;
  const float alpha = log1pf(expf(alpha_u[0]));
  const float inv_s = 0.04419417382415922f;   // 1/sqrt(512)
  int nj[2]; float knj[2], v2j[2];
#pragma unroll
  for (int j = 0; j < 2; ++j) {
    nj[j]  = nBase + wc * 32 + j * 16 + cn;
    knj[j] = kn[nj[j]];
    v2j[j] = vh2[nj[j]];
  }
#pragma unroll
  for (int i = 0; i < 2; ++i)
#pragma unroll
    for (int r = 0; r < 4; ++r) {
      const int s = mBase + wr * 32 + i * 16 + r4 + r;
      const float qns = qn[s], u2 = uh2[s];
      float rs = 0.f;
#pragma unroll
      for (int j = 0; j < 2; ++j) {
        float dE = accE[i][j][r];
        float dH = accH[i][j][r];
        float de   = qns + knj[j] - 2.f * dE;
        float Ac   = 1.f - 2.f * dH + v2j[j];
        float Bc   = 1.f - u2;
        float num2 = Ac * Ac * u2 + Bc * Bc * v2j[j] - 2.f * Ac * Bc * dH;
        float den  = fmaxf(1.f - 2.f * dH + u2 * v2j[j], 1e-5f);
        float frac = sqrtf(fmaxf(num2, 0.f)) / den;
        float nrm  = fminf(frac, 0.999f);
        float dh_  = 2.f * atanhf(nrm);
        float dist = de + alpha * dh_ * dh_;
        float lg   = fminf(fmaxf(-dist * inv_s, -50.f), 0.f);
        float e    = expf(lg);
        unsigned short h, l; bsplit(e, h, l);
        Eh[(size_t)s * S_LEN + nj[j]] = h;
        El[(size_t)s * S_LEN + nj[j]] = l;
        rs += e;
      }
#pragma unroll
      for (int o = 1; o < 16; o <<= 1) rs += __shfl_xor(rs, o);
      if (cn == 0) rowpart[(size_t)s * 32 + blockIdx.x * 2 + wc] = rs;
    }
}

__global__ __launch_bounds__(256) void rowsum_kernel(
    const float* __restrict__ rowpart, float* __restrict__ rinv)
{
  int s = blockIdx.x * 256 + threadIdx.x;
  if (s < S_LEN) {
    float sum = 0.f;
#pragma unroll
    for (int c = 0; c < 32; ++c) sum += rowpart[(size_t)s * 32 + c];
    rinv[s] = 1.f / sum;
  }
}

// ---------------- attn @ V ----------------
__global__ __launch_bounds__(256) void av_mfma(
    const unsigned short* __restrict__ Eh, const unsigned short* __restrict__ El,
    const unsigned short* __restrict__ vTh, const unsigned short* __restrict__ vTl,
    const float* __restrict__ rinv,
    unsigned short* __restrict__ out1h, unsigned short* __restrict__ out1l)
{
  __shared__ unsigned short lds[10240];
  const int mBase = blockIdx.y << 6, nBase = blockIdx.x << 6;
  f32x4 zero = {0.f, 0.f, 0.f, 0.f};
  f32x4 accE[2][2] = {{zero, zero}, {zero, zero}};
  f32x4 accH[2][2] = {{zero, zero}, {zero, zero}};
  mfma_core<32, 32>(Eh, El, S_LEN, vTh, vTl, S_LEN, mBase, nBase, lds, accE, accH);

  const int lane = threadIdx.x & 63, wave = threadIdx.x >> 6;
  const int wr = wave >> 1, wc = wave & 1;
  const int r4 = (lane >> 4) << 2, cn = lane & 15;
#pragma unroll
  for (int i = 0; i < 2; ++i)
#pragma unroll
    for (int r = 0; r < 4; ++r) {
      const int s = mBase + wr * 32 + i * 16 + r4 + r;
      const float sc = rinv[s];
#pragma unroll
      for (int j = 0; j < 2; ++j) {
        const int n = nBase + wc * 32 + j * 16 + cn;
        float val = accE[i][j][r] * sc;
        unsigned short h, l; bsplit(val, h, l);
        out1h[(size_t)s * D_TOT + n] = h;
        out1l[(size_t)s * D_TOT + n] = l;
      }
    }
}

// ---------------- final output GEMM ----------------
__global__ __launch_bounds__(256) void final_mfma(
    const unsigned short* __restrict__ out1h, const unsigned short* __restrict__ out1l,
    const unsigned short* __restrict__ woh,  const unsigned short* __restrict__ wol,
    const float* __restrict__ bo, float* __restrict__ out)
{
  __shared__ unsigned short lds[10240];
  const int mBase = blockIdx.y << 6, nBase = blockIdx.x << 6;
  f32x4 zero = {0.f, 0.f, 0.f, 0.f};
  f32x4 accE[2][2] = {{zero, zero}, {zero, zero}};
  f32x4 accH[2][2] = {{zero, zero}, {zero, zero}};
  mfma_core<16, 16>(out1h, out1l, D_TOT, woh, wol, D_TOT, mBase, nBase, lds, accE, accH);

  const int lane = threadIdx.x & 63, wave = threadIdx.x >> 6;
  const int wr = wave >> 1, wc = wave & 1;
  const int r4 = (lane >> 4) << 2, cn = lane & 15;
#pragma unroll
  for (int i = 0; i < 2; ++i)
#pragma unroll
    for (int j = 0; j < 2; ++j) {
      const int n = nBase + wc * 32 + j * 16 + cn;
      const float b = bo[n];
#pragma unroll
      for (int r = 0; r < 4; ++r) {
        const int s = mBase + wr * 32 + i * 16 + r4 + r;
        out[(size_t)s * D_TOT + n] = accE[i][j][r] + b;
      }
    }
}

extern "C" void kernel_launch(void* const* d_in, const int* in_sizes, int n_in,
                              void* d_out, int out_size, void* d_ws, size_t ws_size,
                              hipStream_t stream)
{
  const float* x   = (const float*)d_in[0];
  const float* wq  = (const float*)d_in[1];
  const float* bq  = (const float*)d_in[2];
  const float* wk  = (const float*)d_in[3];
  const float* bk  = (const float*)d_in[4];
  const float* wv  = (const float*)d_in[5];
  const float* bv  = (const float*)d_in[6];
  const float* wo  = (const float*)d_in[7];
  const float* bo  = (const float*)d_in[8];
  const float* alpha_u = (const float*)d_in[9];
  float* out = (float*)d_out;

  unsigned short* U = (unsigned short*)d_ws;
  unsigned short* xh    = U + 0;         // dead after qkv -> Eh reuses
  unsigned short* xl    = U + 524288;
  unsigned short* wqh   = U + 1048576;   // wq/wk dead after qkv -> El reuses
  unsigned short* wql   = U + 1310720;
  unsigned short* wkh   = U + 1572864;
  unsigned short* wkl   = U + 1835008;
  unsigned short* wvh   = U + 2097152;   // wv dead after qkv -> out1h reuses
  unsigned short* wvl   = U + 2359296;
  unsigned short* woh   = U + 2621440;
  unsigned short* wol   = U + 2883584;
  unsigned short* out1l = U + 3145728;
  unsigned short* Qch   = U + 3670016;
  unsigned short* Qcl   = U + 4194304;
  unsigned short* Kch   = U + 4718592;
  unsigned short* Kcl   = U + 5242880;
  unsigned short* vTh   = U + 5767168;
  unsigned short* vTl   = U + 6291456;
  unsigned short* Eh    = U + 0;         // overlays xh/xl (1M ushort)
  unsigned short* El    = U + 1048576;   // overlays wq/wk hi+lo (1M ushort)
  unsigned short* out1h = U + 2097152;   // overlays wv hi+lo (0.5M ushort)

  float* F = (float*)((char*)d_ws + 13631488);
  float* qh_f    = F;             // 1024*64
  float* kh_f    = F + 65536;
  float* qnpart  = F + 131072;    // 1024*16
  float* knpart  = F + 147456;
  float* qn      = F + 163840;
  float* kn      = F + 164864;
  float* uh2     = F + 165888;
  float* vh2     = F + 166912;
  float* rinv    = F + 167936;
  float* rowpart = F + 168960;    // 1024*32

  convert_kernel<<<dim3(1536), 256, 0, stream>>>(x, wq, wk, wv, wo,
      xh, xl, wqh, wql, wkh, wkl, wvh, wvl, woh, wol);
  qkv_mfma<<<dim3(8, 16, 3), 256, 0, stream>>>(xh, xl, wqh, wql, wkh, wkl, wvh, wvl,
      bq, bk, bv, Qch, Qcl, Kch, Kcl, vTh, vTl, qh_f, kh_f, qnpart, knpart);
  stats_kernel<<<dim3(1024, 2), 64, 0, stream>>>(qh_f, kh_f, qnpart, knpart,
      Qch, Qcl, Kch, Kcl, qn, kn, uh2, vh2);
  score_mfma<<<dim3(16, 16), 256, 0, stream>>>(Qch, Qcl, Kch, Kcl,
      qn, kn, uh2, vh2, alpha_u, Eh, El, rowpart);
  rowsum_kernel<<<dim3(4), 256, 0, stream>>>(rowpart, rinv);
  av_mfma<<<dim3(8, 16), 256, 0, stream>>>(Eh, El, vTh, vTl, rinv, out1h, out1l);
  final_mfma<<<dim3(8, 16), 256, 0, stream>>>(out1h, out1l, woh, wol, bo, out);
}

// Round 3
// 56.253 us; speedup vs baseline: 2.8414x; 1.2385x over previous
//
#include <hip/hip_runtime.h>

#define S_LEN 1024
#define D_TOT 512
#define D_E   448

typedef short bf16x8 __attribute__((ext_vector_type(8)));
typedef float f32x4  __attribute__((ext_vector_type(4)));

__device__ __forceinline__ float wave_sum64(float v) {
#pragma unroll
  for (int o = 32; o > 0; o >>= 1) v += __shfl_xor(v, o);
  return v;
}

// split fp32 into bf16 hi (RNE) + bf16 lo (RNE of remainder)
__device__ __forceinline__ void bsplit(float f, unsigned short &h, unsigned short &l) {
  unsigned u  = __builtin_bit_cast(unsigned, f);
  unsigned ur = u + 0x7fffu + ((u >> 16) & 1u);
  h = (unsigned short)(ur >> 16);
  float fh = __builtin_bit_cast(float, ur & 0xffff0000u);
  float r  = f - fh;
  unsigned u2 = __builtin_bit_cast(unsigned, r);
  l = (unsigned short)((u2 + 0x7fffu + ((u2 >> 16) & 1u)) >> 16);
}

__device__ __forceinline__ void bsplit8(float4 a, float4 b, uint4 &h, uint4 &l) {
  unsigned short h0,h1,h2,h3,h4,h5,h6,h7, l0,l1,l2,l3,l4,l5,l6,l7;
  bsplit(a.x,h0,l0); bsplit(a.y,h1,l1); bsplit(a.z,h2,l2); bsplit(a.w,h3,l3);
  bsplit(b.x,h4,l4); bsplit(b.y,h5,l5); bsplit(b.z,h6,l6); bsplit(b.w,h7,l7);
  h.x = (unsigned)h0 | ((unsigned)h1<<16); h.y = (unsigned)h2 | ((unsigned)h3<<16);
  h.z = (unsigned)h4 | ((unsigned)h5<<16); h.w = (unsigned)h6 | ((unsigned)h7<<16);
  l.x = (unsigned)l0 | ((unsigned)l1<<16); l.y = (unsigned)l2 | ((unsigned)l3<<16);
  l.z = (unsigned)l4 | ((unsigned)l5<<16); l.w = (unsigned)l6 | ((unsigned)l7<<16);
}

// 3-term split MFMA: (Ah+Al)(Bh+Bl) ~= AhBh + AhBl + AlBh
#define MFMA3(ACC)                                                                            \
  _Pragma("unroll") for (int i_ = 0; i_ < 2; ++i_)                                            \
  _Pragma("unroll") for (int j_ = 0; j_ < 2; ++j_) {                                          \
    ACC[i_][j_] = __builtin_amdgcn_mfma_f32_16x16x32_bf16(fAh[i_], fBh[j_], ACC[i_][j_],0,0,0); \
    ACC[i_][j_] = __builtin_amdgcn_mfma_f32_16x16x32_bf16(fAh[i_], fBl[j_], ACC[i_][j_],0,0,0); \
    ACC[i_][j_] = __builtin_amdgcn_mfma_f32_16x16x32_bf16(fAl[i_], fBh[j_], ACC[i_][j_],0,0,0); \
  }

// ================= QKV: q/k/v = x @ W.T + b, fused stats =================
// 64x64 tile, 8 waves = 2(kg) x 2(wr) x 2(wc), BK=32, 8 steps per kg.
__global__ __launch_bounds__(512) void qkv_mfma(
    const float* __restrict__ x,
    const float* __restrict__ wq, const float* __restrict__ bq,
    const float* __restrict__ wk, const float* __restrict__ bk,
    const float* __restrict__ wv, const float* __restrict__ bv,
    unsigned short* __restrict__ Qch, unsigned short* __restrict__ Qcl,
    unsigned short* __restrict__ Kch, unsigned short* __restrict__ Kcl,
    unsigned short* __restrict__ vTh, unsigned short* __restrict__ vTl,
    float* __restrict__ qnpart, float* __restrict__ knpart,
    float* __restrict__ uh2a, float* __restrict__ vh2a)
{
  __shared__ __align__(16) unsigned short stage[20480];   // [2 kg][4 arr][64][40]
  float* fbuf = (float*)stage;                            // [2 kg][64][68]
  const int z = blockIdx.z;
  const float* W; const float* bias;
  if (z == 0)      { W = wq; bias = bq; }
  else if (z == 1) { W = wk; bias = bk; }
  else             { W = wv; bias = bv; }
  const int mBase = blockIdx.y << 6, nBase = blockIdx.x << 6;
  const int t = threadIdx.x, lane = t & 63, wave = t >> 6;
  const int kg = t >> 8, sub = t & 255;
  const int srow = sub >> 2, scol = (sub & 3) << 3;
  const int kgw = wave >> 2, wr = (wave >> 1) & 1, wc = wave & 1;

  const float* Ag = x + (size_t)(mBase + srow) * D_TOT + scol;
  const float* Bg = W + (size_t)(nBase + srow) * D_TOT + scol;
  float4 a0 = *(const float4*)(Ag + kg*256);
  float4 a1 = *(const float4*)(Ag + kg*256 + 4);
  float4 b0 = *(const float4*)(Bg + kg*256);
  float4 b1 = *(const float4*)(Bg + kg*256 + 4);

  f32x4 zero = {0.f,0.f,0.f,0.f};
  f32x4 acc[2][2] = {{zero,zero},{zero,zero}};
  const int sbase = ((kg*4)*64 + srow)*40 + scol;
  const int fa = ((kgw*4)*64 + wr*32 + (lane&15))*40 + ((lane>>4)<<3);
  const int fb = ((kgw*4)*64 + wc*32 + (lane&15))*40 + ((lane>>4)<<3);

#pragma unroll
  for (int r = 0; r < 8; ++r) {
    __syncthreads();
    uint4 hA,lA,hB,lB;
    bsplit8(a0,a1,hA,lA); bsplit8(b0,b1,hB,lB);
    *(uint4*)&stage[sbase       ] = hA;
    *(uint4*)&stage[sbase + 2560] = lA;
    *(uint4*)&stage[sbase + 5120] = hB;
    *(uint4*)&stage[sbase + 7680] = lB;
    if (r + 1 < 8) {
      const int kb = kg*256 + (r+1)*32;
      a0 = *(const float4*)(Ag + kb); a1 = *(const float4*)(Ag + kb + 4);
      b0 = *(const float4*)(Bg + kb); b1 = *(const float4*)(Bg + kb + 4);
    }
    __syncthreads();
    bf16x8 fAh[2],fAl[2],fBh[2],fBl[2];
#pragma unroll
    for (int i = 0; i < 2; ++i) {
      fAh[i] = *(const bf16x8*)&stage[fa + i*640];
      fAl[i] = *(const bf16x8*)&stage[fa + 2560 + i*640];
      fBh[i] = *(const bf16x8*)&stage[fb + 5120 + i*640];
      fBl[i] = *(const bf16x8*)&stage[fb + 7680 + i*640];
    }
    MFMA3(acc);
  }

  // --- cross-kg reduction ---
  __syncthreads();
  {
    const int r0 = wr*32 + ((lane>>4)<<2);
    const int c0 = wc*32 + (lane&15);
#pragma unroll
    for (int i = 0; i < 2; ++i)
#pragma unroll
      for (int j = 0; j < 2; ++j)
#pragma unroll
        for (int g = 0; g < 4; ++g)
          fbuf[kgw*4352 + (r0 + i*16 + g)*68 + c0 + j*16] = acc[i][j][g];
  }
  __syncthreads();
  const int erow = wave << 3;
  float val[8];
  {
    const float b = bias[nBase + lane];
#pragma unroll
    for (int r = 0; r < 8; ++r)
      val[r] = fbuf[(erow+r)*68 + lane] + fbuf[4352 + (erow+r)*68 + lane] + b;
  }

  // --- epilogue ---
  if (z == 2) {
    unsigned short hh[8], ll[8];
#pragma unroll
    for (int r = 0; r < 8; ++r) bsplit(val[r], hh[r], ll[r]);
    const size_t off = (size_t)(nBase + lane) * S_LEN + mBase + erow;
    ushort4 p0{hh[0],hh[1],hh[2],hh[3]}, p1{hh[4],hh[5],hh[6],hh[7]};
    ushort4 q0{ll[0],ll[1],ll[2],ll[3]}, q1{ll[4],ll[5],ll[6],ll[7]};
    *(ushort4*)(vTh + off) = p0; *(ushort4*)(vTh + off + 4) = p1;
    *(ushort4*)(vTl + off) = q0; *(ushort4*)(vTl + off + 4) = q1;
  } else {
    unsigned short* Ch = z ? Kch : Qch;
    unsigned short* Cl = z ? Kcl : Qcl;
    float* np_ = z ? knpart : qnpart;
    float* u2a = z ? vh2a  : uh2a;
    if (blockIdx.x < 7) {
#pragma unroll
      for (int r = 0; r < 8; ++r) {
        const int s = mBase + erow + r;
        unsigned short h,l; bsplit(val[r],h,l);
        Ch[(size_t)s*D_TOT + nBase + lane] = h;
        Cl[(size_t)s*D_TOT + nBase + lane] = l;
        float p = wave_sum64(val[r]*val[r]);
        if (lane == 0) np_[s*8 + blockIdx.x] = p;
      }
    } else {
      // hyperbolic dims: u = project(exp0(val)); ||exp0(v)|| = tanh(||v||)
#pragma unroll
      for (int r = 0; r < 8; ++r) {
        const int s = mBase + erow + r;
        float n2 = wave_sum64(val[r]*val[r]);
        float nn = sqrtf(n2);
        float n  = fmaxf(nn, 1e-5f);
        float th = tanhf(n);
        float pn = th * nn / n;
        float scale = fminf(0.999f / fmaxf(pn, 1e-5f), 1.f);
        float u = (th / n) * scale * val[r];
        float un = pn * scale;
        unsigned short h,l; bsplit(u,h,l);
        Ch[(size_t)s*D_TOT + nBase + lane] = h;
        Cl[(size_t)s*D_TOT + nBase + lane] = l;
        if (lane == 0) u2a[s] = un*un;
      }
    }
  }
}

// ================= scores + exp + partial rowsums =================
// kg0: euclid k[0,224) + hyper k[448,480); kg1: euclid [224,448) + hyper [480,512)
__global__ __launch_bounds__(512) void score_mfma(
    const unsigned short* __restrict__ Qch, const unsigned short* __restrict__ Qcl,
    const unsigned short* __restrict__ Kch, const unsigned short* __restrict__ Kcl,
    const float* __restrict__ qnpart, const float* __restrict__ knpart,
    const float* __restrict__ uh2a, const float* __restrict__ vh2a,
    const float* __restrict__ alpha_u,
    unsigned short* __restrict__ Eh, unsigned short* __restrict__ El,
    float* __restrict__ rowpart)
{
  __shared__ __align__(16) unsigned short stage[20480];
  __shared__ float rowscal[256];    // qn[64] kn[64] u2[64] v2[64]
  float* fbuf = (float*)stage;
  const int t = threadIdx.x, lane = t & 63, wave = t >> 6;
  const int mBase = blockIdx.y << 6, nBase = blockIdx.x << 6;
  if (t < 64) {
    float s_ = 0.f;
#pragma unroll
    for (int c = 0; c < 7; ++c) s_ += qnpart[(mBase+t)*8 + c];
    rowscal[t] = s_;
  } else if (t < 128) {
    float s_ = 0.f;
#pragma unroll
    for (int c = 0; c < 7; ++c) s_ += knpart[(nBase+t-64)*8 + c];
    rowscal[t] = s_;
  } else if (t < 192) rowscal[t] = uh2a[mBase + t - 128];
  else if (t < 256)   rowscal[t] = vh2a[nBase + t - 192];

  const int kg = t >> 8, sub = t & 255;
  const int srow = sub >> 2, scol = (sub & 3) << 3;
  const int kgw = wave >> 2, wr = (wave >> 1) & 1, wc = wave & 1;
  const unsigned short* Agh = Qch + (size_t)(mBase+srow)*D_TOT + scol;
  const unsigned short* Agl = Qcl + (size_t)(mBase+srow)*D_TOT + scol;
  const unsigned short* Bgh = Kch + (size_t)(nBase+srow)*D_TOT + scol;
  const unsigned short* Bgl = Kcl + (size_t)(nBase+srow)*D_TOT + scol;

  int kb = kg*224;
  uint4 hA = *(const uint4*)(Agh + kb), lA = *(const uint4*)(Agl + kb);
  uint4 hB = *(const uint4*)(Bgh + kb), lB = *(const uint4*)(Bgl + kb);

  f32x4 zero = {0.f,0.f,0.f,0.f};
  f32x4 accE[2][2] = {{zero,zero},{zero,zero}};
  f32x4 accH[2][2] = {{zero,zero},{zero,zero}};
  const int sbase = ((kg*4)*64 + srow)*40 + scol;
  const int fa = ((kgw*4)*64 + wr*32 + (lane&15))*40 + ((lane>>4)<<3);
  const int fb = ((kgw*4)*64 + wc*32 + (lane&15))*40 + ((lane>>4)<<3);

#pragma unroll
  for (int r = 0; r < 8; ++r) {
    __syncthreads();
    *(uint4*)&stage[sbase       ] = hA;
    *(uint4*)&stage[sbase + 2560] = lA;
    *(uint4*)&stage[sbase + 5120] = hB;
    *(uint4*)&stage[sbase + 7680] = lB;
    if (r + 1 < 8) {
      kb = (r+1 < 7) ? (kg*224 + (r+1)*32) : (448 + kg*32);
      hA = *(const uint4*)(Agh + kb); lA = *(const uint4*)(Agl + kb);
      hB = *(const uint4*)(Bgh + kb); lB = *(const uint4*)(Bgl + kb);
    }
    __syncthreads();
    bf16x8 fAh[2],fAl[2],fBh[2],fBl[2];
#pragma unroll
    for (int i = 0; i < 2; ++i) {
      fAh[i] = *(const bf16x8*)&stage[fa + i*640];
      fAl[i] = *(const bf16x8*)&stage[fa + 2560 + i*640];
      fBh[i] = *(const bf16x8*)&stage[fb + 5120 + i*640];
      fBl[i] = *(const bf16x8*)&stage[fb + 7680 + i*640];
    }
    if (r < 7) { MFMA3(accE) } else { MFMA3(accH) }
  }

  // --- two-phase cross-kg reduction (E then H) ---
  const int r0 = wr*32 + ((lane>>4)<<2);
  const int c0 = wc*32 + (lane&15);
  const int erow = wave << 3;
  float eE[8], eH[8];
  __syncthreads();
#pragma unroll
  for (int i = 0; i < 2; ++i)
#pragma unroll
    for (int j = 0; j < 2; ++j)
#pragma unroll
      for (int g = 0; g < 4; ++g)
        fbuf[kgw*4352 + (r0 + i*16 + g)*68 + c0 + j*16] = accE[i][j][g];
  __syncthreads();
#pragma unroll
  for (int r = 0; r < 8; ++r)
    eE[r] = fbuf[(erow+r)*68 + lane] + fbuf[4352 + (erow+r)*68 + lane];
  __syncthreads();
#pragma unroll
  for (int i = 0; i < 2; ++i)
#pragma unroll
    for (int j = 0; j < 2; ++j)
#pragma unroll
      for (int g = 0; g < 4; ++g)
        fbuf[kgw*4352 + (r0 + i*16 + g)*68 + c0 + j*16] = accH[i][j][g];
  __syncthreads();
#pragma unroll
  for (int r = 0; r < 8; ++r)
    eH[r] = fbuf[(erow+r)*68 + lane] + fbuf[4352 + (erow+r)*68 + lane];

  // --- transcendental epilogue ---
  const float alpha = log1pf(expf(alpha_u[0]));
  const float inv_s = 0.04419417382415922f;   // 1/sqrt(512)
  const float knl = rowscal[64 + lane], v2 = rowscal[192 + lane];
#pragma unroll
  for (int r = 0; r < 8; ++r) {
    const int s = mBase + erow + r;
    const float qns = rowscal[erow + r], u2 = rowscal[128 + erow + r];
    float de   = qns + knl - 2.f * eE[r];
    float dH   = eH[r];
    float Ac   = 1.f - 2.f*dH + v2;
    float Bc   = 1.f - u2;
    float num2 = Ac*Ac*u2 + Bc*Bc*v2 - 2.f*Ac*Bc*dH;
    float den  = fmaxf(1.f - 2.f*dH + u2*v2, 1e-5f);
    float frac = sqrtf(fmaxf(num2, 0.f)) / den;
    float nrm  = fminf(frac, 0.999f);
    float dh_  = 2.f * atanhf(nrm);
    float dist = de + alpha * dh_ * dh_;
    float lg   = fminf(fmaxf(-dist * inv_s, -50.f), 0.f);
    float e    = expf(lg);
    unsigned short h,l; bsplit(e,h,l);
    Eh[(size_t)s*S_LEN + nBase + lane] = h;
    El[(size_t)s*S_LEN + nBase + lane] = l;
    float rs = wave_sum64(e);
    if (lane == 0) rowpart[s*16 + blockIdx.x] = rs;
  }
}

// ================= attn @ V =================
// 32x64 tile, 8 waves = 4(kg) x 2(wc), K=1024, 8 steps per kg.
__global__ __launch_bounds__(512) void av_mfma(
    const unsigned short* __restrict__ Eh, const unsigned short* __restrict__ El,
    const unsigned short* __restrict__ vTh, const unsigned short* __restrict__ vTl,
    const float* __restrict__ rowpart,
    unsigned short* __restrict__ out1h, unsigned short* __restrict__ out1l)
{
  __shared__ __align__(16) unsigned short stage[30720];  // [4 kg][A 32x40 h/l | B 64x40 h/l]
  __shared__ float rinvl[32];
  float* fbuf = (float*)stage;                           // [4 kg][32][68]
  const int t = threadIdx.x, lane = t & 63, wave = t >> 6;
  const int mBase = blockIdx.y << 5, nBase = blockIdx.x << 6;
  if (t < 32) {
    float s_ = 0.f;
#pragma unroll
    for (int c = 0; c < 16; ++c) s_ += rowpart[(mBase+t)*16 + c];
    rinvl[t] = 1.f / s_;
  }
  const int kg = t >> 7, sub = t & 127;
  const int arow = sub >> 2, acol = (sub & 3) << 3;
  const int brow0 = sub >> 1 >> 1, bcol0 = (sub & 3) << 3;          // idx=sub
  const int brow1 = (sub + 128) >> 2, bcol1 = ((sub + 128) & 3) << 3;
  const int kgw = wave >> 1, wc = wave & 1;

  const unsigned short* Agh = Eh + (size_t)(mBase+arow)*S_LEN + acol;
  const unsigned short* Agl = El + (size_t)(mBase+arow)*S_LEN + acol;
  const unsigned short* B0h = vTh + (size_t)(nBase+brow0)*S_LEN + bcol0;
  const unsigned short* B0l = vTl + (size_t)(nBase+brow0)*S_LEN + bcol0;
  const unsigned short* B1h = vTh + (size_t)(nBase+brow1)*S_LEN + bcol1;
  const unsigned short* B1l = vTl + (size_t)(nBase+brow1)*S_LEN + bcol1;

  int kb = kg*256;
  uint4 ah = *(const uint4*)(Agh + kb), al = *(const uint4*)(Agl + kb);
  uint4 bh0 = *(const uint4*)(B0h + kb), bl0 = *(const uint4*)(B0l + kb);
  uint4 bh1 = *(const uint4*)(B1h + kb), bl1 = *(const uint4*)(B1l + kb);

  f32x4 zero = {0.f,0.f,0.f,0.f};
  f32x4 acc[2][2] = {{zero,zero},{zero,zero}};
  const int sA  = kg*7680 + arow*40 + acol;
  const int sB0 = kg*7680 + 2560 + brow0*40 + bcol0;
  const int sB1 = kg*7680 + 2560 + brow1*40 + bcol1;
  const int fa = kgw*7680 + (lane&15)*40 + ((lane>>4)<<3);
  const int fb = kgw*7680 + 2560 + (wc*32 + (lane&15))*40 + ((lane>>4)<<3);

#pragma unroll
  for (int r = 0; r < 8; ++r) {
    __syncthreads();
    *(uint4*)&stage[sA        ] = ah;  *(uint4*)&stage[sA  + 1280] = al;
    *(uint4*)&stage[sB0       ] = bh0; *(uint4*)&stage[sB0 + 2560] = bl0;
    *(uint4*)&stage[sB1       ] = bh1; *(uint4*)&stage[sB1 + 2560] = bl1;
    if (r + 1 < 8) {
      kb = kg*256 + (r+1)*32;
      ah = *(const uint4*)(Agh + kb); al = *(const uint4*)(Agl + kb);
      bh0 = *(const uint4*)(B0h + kb); bl0 = *(const uint4*)(B0l + kb);
      bh1 = *(const uint4*)(B1h + kb); bl1 = *(const uint4*)(B1l + kb);
    }
    __syncthreads();
    bf16x8 fAh[2],fAl[2],fBh[2],fBl[2];
#pragma unroll
    for (int i = 0; i < 2; ++i) {
      fAh[i] = *(const bf16x8*)&stage[fa + i*640];
      fAl[i] = *(const bf16x8*)&stage[fa + 1280 + i*640];
      fBh[i] = *(const bf16x8*)&stage[fb + i*640];
      fBl[i] = *(const bf16x8*)&stage[fb + 2560 + i*640];
    }
    MFMA3(acc);
  }

  __syncthreads();
  {
    const int r0 = (lane>>4)<<2;
    const int c0 = wc*32 + (lane&15);
#pragma unroll
    for (int i = 0; i < 2; ++i)
#pragma unroll
      for (int j = 0; j < 2; ++j)
#pragma unroll
        for (int g = 0; g < 4; ++g)
          fbuf[kgw*2176 + (r0 + i*16 + g)*68 + c0 + j*16] = acc[i][j][g];
  }
  __syncthreads();
  const int erow = wave << 2;
#pragma unroll
  for (int r = 0; r < 4; ++r) {
    const int row = erow + r;
    float e = fbuf[row*68 + lane] + fbuf[2176 + row*68 + lane]
            + fbuf[4352 + row*68 + lane] + fbuf[6528 + row*68 + lane];
    float v_ = e * rinvl[row];
    unsigned short h,l; bsplit(v_,h,l);
    const int s = mBase + row;
    out1h[(size_t)s*D_TOT + nBase + lane] = h;
    out1l[(size_t)s*D_TOT + nBase + lane] = l;
  }
}

// ================= final: out = out1 @ wo.T + bo =================
__global__ __launch_bounds__(512) void final_mfma(
    const unsigned short* __restrict__ out1h, const unsigned short* __restrict__ out1l,
    const float* __restrict__ wo, const float* __restrict__ bo,
    float* __restrict__ out)
{
  __shared__ __align__(16) unsigned short stage[30720];
  float* fbuf = (float*)stage;
  const int t = threadIdx.x, lane = t & 63, wave = t >> 6;
  const int mBase = blockIdx.y << 5, nBase = blockIdx.x << 6;
  const int kg = t >> 7, sub = t & 127;
  const int arow = sub >> 2, acol = (sub & 3) << 3;
  const int brow0 = sub >> 2, bcol0 = (sub & 3) << 3;
  const int brow1 = (sub + 128) >> 2, bcol1 = ((sub + 128) & 3) << 3;
  const int kgw = wave >> 1, wc = wave & 1;

  const unsigned short* Agh = out1h + (size_t)(mBase+arow)*D_TOT + acol;
  const unsigned short* Agl = out1l + (size_t)(mBase+arow)*D_TOT + acol;
  const float* B0 = wo + (size_t)(nBase+brow0)*D_TOT + bcol0;
  const float* B1 = wo + (size_t)(nBase+brow1)*D_TOT + bcol1;

  int kb = kg*128;
  uint4 ah = *(const uint4*)(Agh + kb), al = *(const uint4*)(Agl + kb);
  float4 b00 = *(const float4*)(B0 + kb), b01 = *(const float4*)(B0 + kb + 4);
  float4 b10 = *(const float4*)(B1 + kb), b11 = *(const float4*)(B1 + kb + 4);

  f32x4 zero = {0.f,0.f,0.f,0.f};
  f32x4 acc[2][2] = {{zero,zero},{zero,zero}};
  const int sA  = kg*7680 + arow*40 + acol;
  const int sB0 = kg*7680 + 2560 + brow0*40 + bcol0;
  const int sB1 = kg*7680 + 2560 + brow1*40 + bcol1;
  const int fa = kgw*7680 + (lane&15)*40 + ((lane>>4)<<3);
  const int fb = kgw*7680 + 2560 + (wc*32 + (lane&15))*40 + ((lane>>4)<<3);

#pragma unroll
  for (int r = 0; r < 4; ++r) {
    __syncthreads();
    uint4 bh0,bl0,bh1,bl1;
    bsplit8(b00,b01,bh0,bl0); bsplit8(b10,b11,bh1,bl1);
    *(uint4*)&stage[sA        ] = ah;  *(uint4*)&stage[sA  + 1280] = al;
    *(uint4*)&stage[sB0       ] = bh0; *(uint4*)&stage[sB0 + 2560] = bl0;
    *(uint4*)&stage[sB1       ] = bh1; *(uint4*)&stage[sB1 + 2560] = bl1;
    if (r + 1 < 4) {
      kb = kg*128 + (r+1)*32;
      ah = *(const uint4*)(Agh + kb); al = *(const uint4*)(Agl + kb);
      b00 = *(const float4*)(B0 + kb); b01 = *(const float4*)(B0 + kb + 4);
      b10 = *(const float4*)(B1 + kb); b11 = *(const float4*)(B1 + kb + 4);
    }
    __syncthreads();
    bf16x8 fAh[2],fAl[2],fBh[2],fBl[2];
#pragma unroll
    for (int i = 0; i < 2; ++i) {
      fAh[i] = *(const bf16x8*)&stage[fa + i*640];
      fAl[i] = *(const bf16x8*)&stage[fa + 1280 + i*640];
      fBh[i] = *(const bf16x8*)&stage[fb + i*640];
      fBl[i] = *(const bf16x8*)&stage[fb + 2560 + i*640];
    }
    MFMA3(acc);
  }

  __syncthreads();
  {
    const int r0 = (lane>>4)<<2;
    const int c0 = wc*32 + (lane&15);
#pragma unroll
    for (int i = 0; i < 2; ++i)
#pragma unroll
      for (int j = 0; j < 2; ++j)
#pragma unroll
        for (int g = 0; g < 4; ++g)
          fbuf[kgw*2176 + (r0 + i*16 + g)*68 + c0 + j*16] = acc[i][j][g];
  }
  __syncthreads();
  const int erow = wave << 2;
  const float b = bo[nBase + lane];
#pragma unroll
  for (int r = 0; r < 4; ++r) {
    const int row = erow + r;
    float e = fbuf[row*68 + lane] + fbuf[2176 + row*68 + lane]
            + fbuf[4352 + row*68 + lane] + fbuf[6528 + row*68 + lane];
    out[(size_t)(mBase+row)*D_TOT + nBase + lane] = e + b;
  }
}

extern "C" void kernel_launch(void* const* d_in, const int* in_sizes, int n_in,
                              void* d_out, int out_size, void* d_ws, size_t ws_size,
                              hipStream_t stream)
{
  const float* x   = (const float*)d_in[0];
  const float* wq  = (const float*)d_in[1];
  const float* bq  = (const float*)d_in[2];
  const float* wk  = (const float*)d_in[3];
  const float* bk  = (const float*)d_in[4];
  const float* wv  = (const float*)d_in[5];
  const float* bv  = (const float*)d_in[6];
  const float* wo  = (const float*)d_in[7];
  const float* bo  = (const float*)d_in[8];
  const float* alpha_u = (const float*)d_in[9];
  float* out = (float*)d_out;

  unsigned short* U = (unsigned short*)d_ws;
  unsigned short* Qch   = U;
  unsigned short* Qcl   = U + 524288;
  unsigned short* Kch   = U + 1048576;
  unsigned short* Kcl   = U + 1572864;
  unsigned short* vTh   = U + 2097152;
  unsigned short* vTl   = U + 2621440;
  unsigned short* Eh    = U + 3145728;
  unsigned short* El    = U + 4194304;
  unsigned short* out1h = U + 5242880;
  unsigned short* out1l = U + 5767168;
  float* F = (float*)(U + 6291456);
  float* qnpart  = F;            // [1024][8]
  float* knpart  = F + 8192;
  float* uh2a    = F + 16384;
  float* vh2a    = F + 17408;
  float* rowpart = F + 18432;    // [1024][16]

  qkv_mfma<<<dim3(8,16,3), 512, 0, stream>>>(x, wq,bq, wk,bk, wv,bv,
      Qch,Qcl,Kch,Kcl,vTh,vTl, qnpart,knpart,uh2a,vh2a);
  score_mfma<<<dim3(16,16), 512, 0, stream>>>(Qch,Qcl,Kch,Kcl,
      qnpart,knpart,uh2a,vh2a, alpha_u, Eh,El, rowpart);
  av_mfma<<<dim3(8,32), 512, 0, stream>>>(Eh,El,vTh,vTl, rowpart, out1h,out1l);
  final_mfma<<<dim3(8,32), 512, 0, stream>>>(out1h,out1l, wo,bo, out);
}

// Round 4
// 50.403 us; speedup vs baseline: 3.1711x; 1.1161x over previous
//
#include <hip/hip_runtime.h>

#define S_LEN 1024
#define D_TOT 512
#define D_E   448

typedef short bf16x8 __attribute__((ext_vector_type(8)));
typedef float f32x4  __attribute__((ext_vector_type(4)));
typedef unsigned short u16;

__device__ __forceinline__ float frcp(float x) {
  float r; asm("v_rcp_f32 %0, %1" : "=v"(r) : "v"(x)); return r;
}

__device__ __forceinline__ float wave_sum64(float v) {
#pragma unroll
  for (int o = 32; o > 0; o >>= 1) v += __shfl_xor(v, o);
  return v;
}

__device__ __forceinline__ u16 bf16rne(float f) {
  unsigned u = __builtin_bit_cast(unsigned, f);
  return (u16)((u + 0x7fffu + ((u >> 16) & 1u)) >> 16);
}

// split fp32 into bf16 hi (RNE) + bf16 lo (RNE of remainder)
__device__ __forceinline__ void bsplit(float f, u16 &h, u16 &l) {
  unsigned u  = __builtin_bit_cast(unsigned, f);
  unsigned ur = u + 0x7fffu + ((u >> 16) & 1u);
  h = (u16)(ur >> 16);
  float fh = __builtin_bit_cast(float, ur & 0xffff0000u);
  float r  = f - fh;
  l = bf16rne(r);
}

// 3-term split MFMA: (Ah+Al)(Bh+Bl) ~= AhBh + AhBl + AlBh
#define MFMA3(ACC)                                                                              \
  _Pragma("unroll") for (int i_ = 0; i_ < 2; ++i_)                                              \
  _Pragma("unroll") for (int j_ = 0; j_ < 2; ++j_) {                                            \
    ACC[i_][j_] = __builtin_amdgcn_mfma_f32_16x16x32_bf16(fAh[i_], fBh[j_], ACC[i_][j_],0,0,0); \
    ACC[i_][j_] = __builtin_amdgcn_mfma_f32_16x16x32_bf16(fAh[i_], fBl[j_], ACC[i_][j_],0,0,0); \
    ACC[i_][j_] = __builtin_amdgcn_mfma_f32_16x16x32_bf16(fAl[i_], fBh[j_], ACC[i_][j_],0,0,0); \
  }

// 2-term: A hi-only (E in [0,1])
#define MFMA2(ACC)                                                                              \
  _Pragma("unroll") for (int i_ = 0; i_ < 2; ++i_)                                              \
  _Pragma("unroll") for (int j_ = 0; j_ < 2; ++j_) {                                            \
    ACC[i_][j_] = __builtin_amdgcn_mfma_f32_16x16x32_bf16(fAh[i_], fBh[j_], ACC[i_][j_],0,0,0); \
    ACC[i_][j_] = __builtin_amdgcn_mfma_f32_16x16x32_bf16(fAh[i_], fBl[j_], ACC[i_][j_],0,0,0); \
  }

// ================= convert: one hi/lo split per element, memory-bound =================
__global__ __launch_bounds__(256) void convert_kernel(
    const float* __restrict__ x,  const float* __restrict__ wq,
    const float* __restrict__ wk, const float* __restrict__ wv,
    const float* __restrict__ wo,
    u16* __restrict__ xh,  u16* __restrict__ xl,
    u16* __restrict__ wqh, u16* __restrict__ wql,
    u16* __restrict__ wkh, u16* __restrict__ wkl,
    u16* __restrict__ wvh, u16* __restrict__ wvl,
    u16* __restrict__ woh, u16* __restrict__ wol)
{
  int i = (blockIdx.x * 256 + threadIdx.x) * 4;
  const float* src; u16 *dh, *dl; int off;
  if      (i <  524288) { src = x;  dh = xh;  dl = xl;  off = i; }
  else if (i <  786432) { src = wq; dh = wqh; dl = wql; off = i -  524288; }
  else if (i < 1048576) { src = wk; dh = wkh; dl = wkl; off = i -  786432; }
  else if (i < 1310720) { src = wv; dh = wvh; dl = wvl; off = i - 1048576; }
  else                  { src = wo; dh = woh; dl = wol; off = i - 1310720; }
  float4 v = *(const float4*)(src + off);
  ushort4 h4, l4;
  bsplit(v.x, h4.x, l4.x); bsplit(v.y, h4.y, l4.y);
  bsplit(v.z, h4.z, l4.z); bsplit(v.w, h4.w, l4.w);
  *(ushort4*)(dh + off) = h4;
  *(ushort4*)(dl + off) = l4;
}

// ================= QKV: q/k/v = x @ W.T + b, fused stats =================
// 64x64 tile, 8 waves = 2(kg) x 2(wr) x 2(wc), BK=32, dbuf LDS, 8 steps.
__global__ __launch_bounds__(512) void qkv_mfma(
    const u16* __restrict__ xh,  const u16* __restrict__ xl,
    const u16* __restrict__ wqh, const u16* __restrict__ wql,
    const u16* __restrict__ wkh, const u16* __restrict__ wkl,
    const u16* __restrict__ wvh, const u16* __restrict__ wvl,
    const float* __restrict__ bq, const float* __restrict__ bk, const float* __restrict__ bv,
    u16* __restrict__ Qch, u16* __restrict__ Qcl,
    u16* __restrict__ Kch, u16* __restrict__ Kcl,
    u16* __restrict__ vTh, u16* __restrict__ vTl,
    float* __restrict__ qnpart, float* __restrict__ knpart,
    float* __restrict__ uh2a, float* __restrict__ vh2a)
{
  __shared__ __align__(16) u16 stage[2][20480];   // per buf: [2 kg][Ah|Al|Bh|Bl][64][40]
  float* fbuf = (float*)stage;                    // [2 kg][64][68]
  const int z = blockIdx.z;
  const u16 *Bh_, *Bl_; const float* bias;
  if (z == 0)      { Bh_ = wqh; Bl_ = wql; bias = bq; }
  else if (z == 1) { Bh_ = wkh; Bl_ = wkl; bias = bk; }
  else             { Bh_ = wvh; Bl_ = wvl; bias = bv; }
  const int mBase = blockIdx.y << 6, nBase = blockIdx.x << 6;
  const int t = threadIdx.x, lane = t & 63, wave = t >> 6;
  const int kg = t >> 8, sub = t & 255;
  const int srow = sub >> 2, scol = (sub & 3) << 3;
  const int kgw = wave >> 2, wr = (wave >> 1) & 1, wc = wave & 1;

  const u16* Agh = xh  + (size_t)(mBase + srow) * D_TOT + scol + kg * 256;
  const u16* Agl = xl  + (size_t)(mBase + srow) * D_TOT + scol + kg * 256;
  const u16* Bgh = Bh_ + (size_t)(nBase + srow) * D_TOT + scol + kg * 256;
  const u16* Bgl = Bl_ + (size_t)(nBase + srow) * D_TOT + scol + kg * 256;

  const int sb = kg * 10240 + srow * 40 + scol;
  const int fa = kgw * 10240 + (wr * 32 + (lane & 15)) * 40 + ((lane >> 4) << 3);
  const int fb = kgw * 10240 + (wc * 32 + (lane & 15)) * 40 + ((lane >> 4) << 3);

  uint4 rAh = *(const uint4*)Agh, rAl = *(const uint4*)Agl;
  uint4 rBh = *(const uint4*)Bgh, rBl = *(const uint4*)Bgl;
  *(uint4*)&stage[0][sb       ] = rAh;
  *(uint4*)&stage[0][sb + 2560] = rAl;
  *(uint4*)&stage[0][sb + 5120] = rBh;
  *(uint4*)&stage[0][sb + 7680] = rBl;
  rAh = *(const uint4*)(Agh + 32); rAl = *(const uint4*)(Agl + 32);
  rBh = *(const uint4*)(Bgh + 32); rBl = *(const uint4*)(Bgl + 32);

  f32x4 zero = {0.f,0.f,0.f,0.f};
  f32x4 acc[2][2] = {{zero,zero},{zero,zero}};
#pragma unroll
  for (int r = 0; r < 8; ++r) {
    __syncthreads();
    const u16* bufr = stage[r & 1];
    bf16x8 fAh[2], fAl[2], fBh[2], fBl[2];
#pragma unroll
    for (int i = 0; i < 2; ++i) {
      fAh[i] = *(const bf16x8*)&bufr[fa        + i*640];
      fAl[i] = *(const bf16x8*)&bufr[fa + 2560 + i*640];
      fBh[i] = *(const bf16x8*)&bufr[fb + 5120 + i*640];
      fBl[i] = *(const bf16x8*)&bufr[fb + 7680 + i*640];
    }
    if (r + 1 < 8) {
      u16* bufw = stage[(r + 1) & 1];
      *(uint4*)&bufw[sb       ] = rAh;
      *(uint4*)&bufw[sb + 2560] = rAl;
      *(uint4*)&bufw[sb + 5120] = rBh;
      *(uint4*)&bufw[sb + 7680] = rBl;
      if (r + 2 < 8) {
        const int o = (r + 2) * 32;
        rAh = *(const uint4*)(Agh + o); rAl = *(const uint4*)(Agl + o);
        rBh = *(const uint4*)(Bgh + o); rBl = *(const uint4*)(Bgl + o);
      }
    }
    MFMA3(acc);
  }

  // --- cross-kg reduction (single round-trip) ---
  __syncthreads();
  {
    const int r0 = wr*32 + ((lane>>4)<<2);
    const int c0 = wc*32 + (lane&15);
#pragma unroll
    for (int i = 0; i < 2; ++i)
#pragma unroll
      for (int j = 0; j < 2; ++j)
#pragma unroll
        for (int g = 0; g < 4; ++g)
          fbuf[kgw*4352 + (r0 + i*16 + g)*68 + c0 + j*16] = acc[i][j][g];
  }
  __syncthreads();
  const int erow = wave << 3;
  float val[8];
  {
    const float b = bias[nBase + lane];
#pragma unroll
    for (int r = 0; r < 8; ++r)
      val[r] = fbuf[(erow+r)*68 + lane] + fbuf[4352 + (erow+r)*68 + lane] + b;
  }

  // --- epilogue ---
  if (z == 2) {
    u16 hh[8], ll[8];
#pragma unroll
    for (int r = 0; r < 8; ++r) bsplit(val[r], hh[r], ll[r]);
    const size_t off = (size_t)(nBase + lane) * S_LEN + mBase + erow;
    ushort4 p0{hh[0],hh[1],hh[2],hh[3]}, p1{hh[4],hh[5],hh[6],hh[7]};
    ushort4 q0{ll[0],ll[1],ll[2],ll[3]}, q1{ll[4],ll[5],ll[6],ll[7]};
    *(ushort4*)(vTh + off) = p0; *(ushort4*)(vTh + off + 4) = p1;
    *(ushort4*)(vTl + off) = q0; *(ushort4*)(vTl + off + 4) = q1;
  } else {
    u16* Ch = z ? Kch : Qch;
    u16* Cl = z ? Kcl : Qcl;
    float* np_ = z ? knpart : qnpart;
    float* u2a = z ? vh2a  : uh2a;
    if (blockIdx.x < 7) {
#pragma unroll
      for (int r = 0; r < 8; ++r) {
        const int s = mBase + erow + r;
        u16 h,l; bsplit(val[r],h,l);
        Ch[(size_t)s*D_TOT + nBase + lane] = h;
        Cl[(size_t)s*D_TOT + nBase + lane] = l;
        float p = wave_sum64(val[r]*val[r]);
        if (lane == 0) np_[s*8 + blockIdx.x] = p;
      }
    } else {
      // hyperbolic dims: u = project(exp0(val)); ||exp0(v)|| = tanh(||v||)
#pragma unroll
      for (int r = 0; r < 8; ++r) {
        const int s = mBase + erow + r;
        float n2 = wave_sum64(val[r]*val[r]);
        float nn = sqrtf(n2);
        float n  = fmaxf(nn, 1e-5f);
        float e2n = __expf(2.f*n);
        float th  = 1.f - 2.f*frcp(e2n + 1.f);
        float rn  = frcp(n);
        float pn  = th * nn * rn;
        float scale = fminf(0.999f * frcp(fmaxf(pn, 1e-5f)), 1.f);
        float u = th * rn * scale * val[r];
        float un = pn * scale;
        u16 h,l; bsplit(u,h,l);
        Ch[(size_t)s*D_TOT + nBase + lane] = h;
        Cl[(size_t)s*D_TOT + nBase + lane] = l;
        if (lane == 0) u2a[s] = un*un;
      }
    }
  }
}

// ================= scores + exp + partial rowsums =================
__global__ __launch_bounds__(512) void score_mfma(
    const u16* __restrict__ Qch, const u16* __restrict__ Qcl,
    const u16* __restrict__ Kch, const u16* __restrict__ Kcl,
    const float* __restrict__ qnpart, const float* __restrict__ knpart,
    const float* __restrict__ uh2a, const float* __restrict__ vh2a,
    const float* __restrict__ alpha_u,
    u16* __restrict__ Eh, float* __restrict__ rowpart)
{
  __shared__ __align__(16) u16 stage[2][20480];
  __shared__ float rowscal[256];    // qn[64] kn[64] u2[64] v2[64]
  float* fbuf = (float*)stage;      // fbufE @0, fbufH @8704 floats
  const int t = threadIdx.x, lane = t & 63, wave = t >> 6;
  const int mBase = blockIdx.y << 6, nBase = blockIdx.x << 6;
  if (t < 64) {
    float s_ = 0.f;
#pragma unroll
    for (int c = 0; c < 7; ++c) s_ += qnpart[(mBase+t)*8 + c];
    rowscal[t] = s_;
  } else if (t < 128) {
    float s_ = 0.f;
#pragma unroll
    for (int c = 0; c < 7; ++c) s_ += knpart[(nBase+t-64)*8 + c];
    rowscal[t] = s_;
  } else if (t < 192) rowscal[t] = uh2a[mBase + t - 128];
  else if (t < 256)   rowscal[t] = vh2a[nBase + t - 192];

  const int kg = t >> 8, sub = t & 255;
  const int srow = sub >> 2, scol = (sub & 3) << 3;
  const int kgw = wave >> 2, wr = (wave >> 1) & 1, wc = wave & 1;
  const u16* Agh = Qch + (size_t)(mBase+srow)*D_TOT + scol;
  const u16* Agl = Qcl + (size_t)(mBase+srow)*D_TOT + scol;
  const u16* Bgh = Kch + (size_t)(nBase+srow)*D_TOT + scol;
  const u16* Bgl = Kcl + (size_t)(nBase+srow)*D_TOT + scol;

  const int sb = kg * 10240 + srow * 40 + scol;
  const int fa = kgw * 10240 + (wr * 32 + (lane & 15)) * 40 + ((lane >> 4) << 3);
  const int fb = kgw * 10240 + (wc * 32 + (lane & 15)) * 40 + ((lane >> 4) << 3);

  // kb(r): r<7 -> euclid chunk, r==7 -> hyper chunk
  int kb0 = kg * 224;
  uint4 rAh = *(const uint4*)(Agh + kb0), rAl = *(const uint4*)(Agl + kb0);
  uint4 rBh = *(const uint4*)(Bgh + kb0), rBl = *(const uint4*)(Bgl + kb0);
  *(uint4*)&stage[0][sb       ] = rAh;
  *(uint4*)&stage[0][sb + 2560] = rAl;
  *(uint4*)&stage[0][sb + 5120] = rBh;
  *(uint4*)&stage[0][sb + 7680] = rBl;
  int kb1 = kg * 224 + 32;
  rAh = *(const uint4*)(Agh + kb1); rAl = *(const uint4*)(Agl + kb1);
  rBh = *(const uint4*)(Bgh + kb1); rBl = *(const uint4*)(Bgl + kb1);

  f32x4 zero = {0.f,0.f,0.f,0.f};
  f32x4 accE[2][2] = {{zero,zero},{zero,zero}};
  f32x4 accH[2][2] = {{zero,zero},{zero,zero}};
#pragma unroll
  for (int r = 0; r < 8; ++r) {
    __syncthreads();
    const u16* bufr = stage[r & 1];
    bf16x8 fAh[2], fAl[2], fBh[2], fBl[2];
#pragma unroll
    for (int i = 0; i < 2; ++i) {
      fAh[i] = *(const bf16x8*)&bufr[fa        + i*640];
      fAl[i] = *(const bf16x8*)&bufr[fa + 2560 + i*640];
      fBh[i] = *(const bf16x8*)&bufr[fb + 5120 + i*640];
      fBl[i] = *(const bf16x8*)&bufr[fb + 7680 + i*640];
    }
    if (r + 1 < 8) {
      u16* bufw = stage[(r + 1) & 1];
      *(uint4*)&bufw[sb       ] = rAh;
      *(uint4*)&bufw[sb + 2560] = rAl;
      *(uint4*)&bufw[sb + 5120] = rBh;
      *(uint4*)&bufw[sb + 7680] = rBl;
      if (r + 2 < 8) {
        const int o = (r + 2 < 7) ? (kg*224 + (r+2)*32) : (448 + kg*32);
        rAh = *(const uint4*)(Agh + o); rAl = *(const uint4*)(Agl + o);
        rBh = *(const uint4*)(Bgh + o); rBl = *(const uint4*)(Bgl + o);
      }
    }
    if (r < 7) { MFMA3(accE) } else { MFMA3(accH) }
  }

  // --- single round-trip cross-kg reduction of E and H ---
  __syncthreads();
  {
    const int r0 = wr*32 + ((lane>>4)<<2);
    const int c0 = wc*32 + (lane&15);
#pragma unroll
    for (int i = 0; i < 2; ++i)
#pragma unroll
      for (int j = 0; j < 2; ++j)
#pragma unroll
        for (int g = 0; g < 4; ++g) {
          fbuf[       kgw*4352 + (r0 + i*16 + g)*68 + c0 + j*16] = accE[i][j][g];
          fbuf[8704 + kgw*4352 + (r0 + i*16 + g)*68 + c0 + j*16] = accH[i][j][g];
        }
  }
  __syncthreads();
  const int erow = wave << 3;
  float eE[8], eH[8];
#pragma unroll
  for (int r = 0; r < 8; ++r) {
    eE[r] = fbuf[(erow+r)*68 + lane] + fbuf[4352 + (erow+r)*68 + lane];
    eH[r] = fbuf[8704 + (erow+r)*68 + lane] + fbuf[8704 + 4352 + (erow+r)*68 + lane];
  }

  // --- transcendental epilogue (fast intrinsics) ---
  const float alpha = __logf(1.f + __expf(alpha_u[0]));
  const float inv_s = 0.04419417382415922f;   // 1/sqrt(512)
  const float knl = rowscal[64 + lane], v2 = rowscal[192 + lane];
#pragma unroll
  for (int r = 0; r < 8; ++r) {
    const int s = mBase + erow + r;
    const float qns = rowscal[erow + r], u2 = rowscal[128 + erow + r];
    float de   = qns + knl - 2.f * eE[r];
    float dH   = eH[r];
    float Ac   = 1.f - 2.f*dH + v2;
    float Bc   = 1.f - u2;
    float num2 = Ac*Ac*u2 + Bc*Bc*v2 - 2.f*Ac*Bc*dH;
    float den  = fmaxf(1.f - 2.f*dH + u2*v2, 1e-5f);
    float frac = sqrtf(fmaxf(num2, 0.f)) * frcp(den);
    float nrm  = fminf(frac, 0.999f);
    float dh_  = __logf((1.f + nrm) * frcp(1.f - nrm));   // = 2*atanh(nrm)
    float dist = de + alpha * dh_ * dh_;
    float lg   = fminf(fmaxf(-dist * inv_s, -50.f), 0.f);
    float e    = __expf(lg);
    Eh[(size_t)s*S_LEN + nBase + lane] = bf16rne(e);
    float rs = wave_sum64(e);
    if (lane == 0) rowpart[s*16 + blockIdx.x] = rs;
  }
}

// ================= attn @ V (E hi-only) =================
// 32x64 tile, 8 waves = 4(kg) x 2(wc), K=1024, dbuf, 8 steps.
__global__ __launch_bounds__(512) void av_mfma(
    const u16* __restrict__ Eh,
    const u16* __restrict__ vTh, const u16* __restrict__ vTl,
    const float* __restrict__ rowpart,
    u16* __restrict__ out1h, u16* __restrict__ out1l)
{
  __shared__ __align__(16) u16 stage[2][25600];  // per buf per kg: [Ah 1280][Bh 2560][Bl 2560]
  __shared__ float rinvl[32];
  float* fbuf = (float*)stage;                   // [4 kg][32][68]
  const int t = threadIdx.x, lane = t & 63, wave = t >> 6;
  const int mBase = blockIdx.y << 5, nBase = blockIdx.x << 6;
  if (t < 32) {
    float s_ = 0.f;
#pragma unroll
    for (int c = 0; c < 16; ++c) s_ += rowpart[(mBase+t)*16 + c];
    rinvl[t] = 1.f / s_;
  }
  const int kg = t >> 7, sub = t & 127;
  const int arow = sub >> 2, acol = (sub & 3) << 3;
  const int brow0 = sub >> 2, bcol0 = (sub & 3) << 3;
  const int brow1 = (sub + 128) >> 2, bcol1 = ((sub + 128) & 3) << 3;
  const int kgw = wave >> 1, wc = wave & 1;

  const u16* Ag  = Eh  + (size_t)(mBase+arow)*S_LEN + acol + kg*256;
  const u16* B0h = vTh + (size_t)(nBase+brow0)*S_LEN + bcol0 + kg*256;
  const u16* B0l = vTl + (size_t)(nBase+brow0)*S_LEN + bcol0 + kg*256;
  const u16* B1h = vTh + (size_t)(nBase+brow1)*S_LEN + bcol1 + kg*256;
  const u16* B1l = vTl + (size_t)(nBase+brow1)*S_LEN + bcol1 + kg*256;

  const int sA  = kg*6400 + arow*40 + acol;
  const int sB0 = kg*6400 + 1280 + brow0*40 + bcol0;
  const int sB1 = kg*6400 + 1280 + brow1*40 + bcol1;
  const int fa  = kgw*6400 + (lane&15)*40 + ((lane>>4)<<3);
  const int fbh = kgw*6400 + 1280 + (wc*32 + (lane&15))*40 + ((lane>>4)<<3);

  uint4 rA = *(const uint4*)Ag;
  uint4 rb0h = *(const uint4*)B0h, rb0l = *(const uint4*)B0l;
  uint4 rb1h = *(const uint4*)B1h, rb1l = *(const uint4*)B1l;
  *(uint4*)&stage[0][sA        ] = rA;
  *(uint4*)&stage[0][sB0       ] = rb0h; *(uint4*)&stage[0][sB0 + 2560] = rb0l;
  *(uint4*)&stage[0][sB1       ] = rb1h; *(uint4*)&stage[0][sB1 + 2560] = rb1l;
  rA = *(const uint4*)(Ag + 32);
  rb0h = *(const uint4*)(B0h + 32); rb0l = *(const uint4*)(B0l + 32);
  rb1h = *(const uint4*)(B1h + 32); rb1l = *(const uint4*)(B1l + 32);

  f32x4 zero = {0.f,0.f,0.f,0.f};
  f32x4 acc[2][2] = {{zero,zero},{zero,zero}};
#pragma unroll
  for (int r = 0; r < 8; ++r) {
    __syncthreads();
    const u16* bufr = stage[r & 1];
    bf16x8 fAh[2], fBh[2], fBl[2];
#pragma unroll
    for (int i = 0; i < 2; ++i) {
      fAh[i] = *(const bf16x8*)&bufr[fa         + i*640];
      fBh[i] = *(const bf16x8*)&bufr[fbh        + i*640];
      fBl[i] = *(const bf16x8*)&bufr[fbh + 2560 + i*640];
    }
    if (r + 1 < 8) {
      u16* bufw = stage[(r + 1) & 1];
      *(uint4*)&bufw[sA        ] = rA;
      *(uint4*)&bufw[sB0       ] = rb0h; *(uint4*)&bufw[sB0 + 2560] = rb0l;
      *(uint4*)&bufw[sB1       ] = rb1h; *(uint4*)&bufw[sB1 + 2560] = rb1l;
      if (r + 2 < 8) {
        const int o = (r + 2) * 32;
        rA = *(const uint4*)(Ag + o);
        rb0h = *(const uint4*)(B0h + o); rb0l = *(const uint4*)(B0l + o);
        rb1h = *(const uint4*)(B1h + o); rb1l = *(const uint4*)(B1l + o);
      }
    }
    MFMA2(acc);
  }

  __syncthreads();
  {
    const int r0 = (lane>>4)<<2;
    const int c0 = wc*32 + (lane&15);
#pragma unroll
    for (int i = 0; i < 2; ++i)
#pragma unroll
      for (int j = 0; j < 2; ++j)
#pragma unroll
        for (int g = 0; g < 4; ++g)
          fbuf[kgw*2176 + (r0 + i*16 + g)*68 + c0 + j*16] = acc[i][j][g];
  }
  __syncthreads();
  const int erow = wave << 2;
#pragma unroll
  for (int r = 0; r < 4; ++r) {
    const int row = erow + r;
    float e = fbuf[row*68 + lane] + fbuf[2176 + row*68 + lane]
            + fbuf[4352 + row*68 + lane] + fbuf[6528 + row*68 + lane];
    float v_ = e * rinvl[row];
    u16 h,l; bsplit(v_,h,l);
    const int s = mBase + row;
    out1h[(size_t)s*D_TOT + nBase + lane] = h;
    out1l[(size_t)s*D_TOT + nBase + lane] = l;
  }
}

// ================= final: out = out1 @ wo.T + bo =================
__global__ __launch_bounds__(512) void final_mfma(
    const u16* __restrict__ out1h, const u16* __restrict__ out1l,
    const u16* __restrict__ woh,  const u16* __restrict__ wol,
    const float* __restrict__ bo, float* __restrict__ out)
{
  __shared__ __align__(16) u16 stage[2][30720];  // per buf per kg: [Ah 1280][Al 1280][Bh 2560][Bl 2560]
  float* fbuf = (float*)stage;
  const int t = threadIdx.x, lane = t & 63, wave = t >> 6;
  const int mBase = blockIdx.y << 5, nBase = blockIdx.x << 6;
  const int kg = t >> 7, sub = t & 127;
  const int arow = sub >> 2, acol = (sub & 3) << 3;
  const int brow0 = sub >> 2, bcol0 = (sub & 3) << 3;
  const int brow1 = (sub + 128) >> 2, bcol1 = ((sub + 128) & 3) << 3;
  const int kgw = wave >> 1, wc = wave & 1;

  const u16* Agh = out1h + (size_t)(mBase+arow)*D_TOT + acol + kg*128;
  const u16* Agl = out1l + (size_t)(mBase+arow)*D_TOT + acol + kg*128;
  const u16* B0h = woh + (size_t)(nBase+brow0)*D_TOT + bcol0 + kg*128;
  const u16* B0l = wol + (size_t)(nBase+brow0)*D_TOT + bcol0 + kg*128;
  const u16* B1h = woh + (size_t)(nBase+brow1)*D_TOT + bcol1 + kg*128;
  const u16* B1l = wol + (size_t)(nBase+brow1)*D_TOT + bcol1 + kg*128;

  const int sA  = kg*7680 + arow*40 + acol;
  const int sB0 = kg*7680 + 2560 + brow0*40 + bcol0;
  const int sB1 = kg*7680 + 2560 + brow1*40 + bcol1;
  const int fa  = kgw*7680 + (lane&15)*40 + ((lane>>4)<<3);
  const int fbh = kgw*7680 + 2560 + (wc*32 + (lane&15))*40 + ((lane>>4)<<3);

  uint4 rah = *(const uint4*)Agh, ral = *(const uint4*)Agl;
  uint4 rb0h = *(const uint4*)B0h, rb0l = *(const uint4*)B0l;
  uint4 rb1h = *(const uint4*)B1h, rb1l = *(const uint4*)B1l;
  *(uint4*)&stage[0][sA        ] = rah; *(uint4*)&stage[0][sA  + 1280] = ral;
  *(uint4*)&stage[0][sB0       ] = rb0h; *(uint4*)&stage[0][sB0 + 2560] = rb0l;
  *(uint4*)&stage[0][sB1       ] = rb1h; *(uint4*)&stage[0][sB1 + 2560] = rb1l;
  rah = *(const uint4*)(Agh + 32); ral = *(const uint4*)(Agl + 32);
  rb0h = *(const uint4*)(B0h + 32); rb0l = *(const uint4*)(B0l + 32);
  rb1h = *(const uint4*)(B1h + 32); rb1l = *(const uint4*)(B1l + 32);

  f32x4 zero = {0.f,0.f,0.f,0.f};
  f32x4 acc[2][2] = {{zero,zero},{zero,zero}};
#pragma unroll
  for (int r = 0; r < 4; ++r) {
    __syncthreads();
    const u16* bufr = stage[r & 1];
    bf16x8 fAh[2], fAl[2], fBh[2], fBl[2];
#pragma unroll
    for (int i = 0; i < 2; ++i) {
      fAh[i] = *(const bf16x8*)&bufr[fa         + i*640];
      fAl[i] = *(const bf16x8*)&bufr[fa + 1280  + i*640];
      fBh[i] = *(const bf16x8*)&bufr[fbh        + i*640];
      fBl[i] = *(const bf16x8*)&bufr[fbh + 2560 + i*640];
    }
    if (r + 1 < 4) {
      u16* bufw = stage[(r + 1) & 1];
      *(uint4*)&bufw[sA        ] = rah; *(uint4*)&bufw[sA  + 1280] = ral;
      *(uint4*)&bufw[sB0       ] = rb0h; *(uint4*)&bufw[sB0 + 2560] = rb0l;
      *(uint4*)&bufw[sB1       ] = rb1h; *(uint4*)&bufw[sB1 + 2560] = rb1l;
      if (r + 2 < 4) {
        const int o = (r + 2) * 32;
        rah = *(const uint4*)(Agh + o); ral = *(const uint4*)(Agl + o);
        rb0h = *(const uint4*)(B0h + o); rb0l = *(const uint4*)(B0l + o);
        rb1h = *(const uint4*)(B1h + o); rb1l = *(const uint4*)(B1l + o);
      }
    }
    MFMA3(acc);
  }

  __syncthreads();
  {
    const int r0 = (lane>>4)<<2;
    const int c0 = wc*32 + (lane&15);
#pragma unroll
    for (int i = 0; i < 2; ++i)
#pragma unroll
      for (int j = 0; j < 2; ++j)
#pragma unroll
        for (int g = 0; g < 4; ++g)
          fbuf[kgw*2176 + (r0 + i*16 + g)*68 + c0 + j*16] = acc[i][j][g];
  }
  __syncthreads();
  const int erow = wave << 2;
  const float b = bo[nBase + lane];
#pragma unroll
  for (int r = 0; r < 4; ++r) {
    const int row = erow + r;
    float e = fbuf[row*68 + lane] + fbuf[2176 + row*68 + lane]
            + fbuf[4352 + row*68 + lane] + fbuf[6528 + row*68 + lane];
    out[(size_t)(mBase+row)*D_TOT + nBase + lane] = e + b;
  }
}

extern "C" void kernel_launch(void* const* d_in, const int* in_sizes, int n_in,
                              void* d_out, int out_size, void* d_ws, size_t ws_size,
                              hipStream_t stream)
{
  const float* x   = (const float*)d_in[0];
  const float* wq  = (const float*)d_in[1];
  const float* bq  = (const float*)d_in[2];
  const float* wk  = (const float*)d_in[3];
  const float* bk  = (const float*)d_in[4];
  const float* wv  = (const float*)d_in[5];
  const float* bv  = (const float*)d_in[6];
  const float* wo  = (const float*)d_in[7];
  const float* bo  = (const float*)d_in[8];
  const float* alpha_u = (const float*)d_in[9];
  float* out = (float*)d_out;

  u16* U = (u16*)d_ws;
  u16* xh    = U + 0;
  u16* xl    = U + 524288;
  u16* wqh   = U + 1048576;
  u16* wql   = U + 1310720;
  u16* wkh   = U + 1572864;
  u16* wkl   = U + 1835008;
  u16* wvh   = U + 2097152;
  u16* wvl   = U + 2359296;
  u16* woh   = U + 2621440;
  u16* wol   = U + 2883584;
  u16* Qch   = U + 3145728;
  u16* Qcl   = U + 3670016;
  u16* Kch   = U + 4194304;
  u16* Kcl   = U + 4718592;
  u16* vTh   = U + 5242880;
  u16* vTl   = U + 5767168;
  u16* Eh    = U + 6291456;   // 1048576
  u16* out1h = U + 7340032;
  u16* out1l = U + 7864320;
  float* F = (float*)(U + 8388608);
  float* qnpart  = F;          // [1024][8]
  float* knpart  = F + 8192;
  float* uh2a    = F + 16384;
  float* vh2a    = F + 17408;
  float* rowpart = F + 18432;  // [1024][16]

  convert_kernel<<<dim3(1536), 256, 0, stream>>>(x, wq, wk, wv, wo,
      xh, xl, wqh, wql, wkh, wkl, wvh, wvl, woh, wol);
  qkv_mfma<<<dim3(8,16,3), 512, 0, stream>>>(xh, xl, wqh, wql, wkh, wkl, wvh, wvl,
      bq, bk, bv, Qch, Qcl, Kch, Kcl, vTh, vTl, qnpart, knpart, uh2a, vh2a);
  score_mfma<<<dim3(16,16), 512, 0, stream>>>(Qch, Qcl, Kch, Kcl,
      qnpart, knpart, uh2a, vh2a, alpha_u, Eh, rowpart);
  av_mfma<<<dim3(8,32), 512, 0, stream>>>(Eh, vTh, vTl, rowpart, out1h, out1l);
  final_mfma<<<dim3(8,32), 512, 0, stream>>>(out1h, out1l, woh, wol, bo, out);
}

// Round 5
// 46.729 us; speedup vs baseline: 3.4205x; 1.0786x over previous
//
#include <hip/hip_runtime.h>

#define S_LEN 1024
#define D_TOT 512
#define D_E   448

typedef short bf16x8 __attribute__((ext_vector_type(8)));
typedef float f32x4  __attribute__((ext_vector_type(4)));
typedef unsigned short u16;

__device__ __forceinline__ float frcp(float x) {
  float r; asm("v_rcp_f32 %0, %1" : "=v"(r) : "v"(x)); return r;
}

__device__ __forceinline__ float wave_sum64(float v) {
#pragma unroll
  for (int o = 32; o > 0; o >>= 1) v += __shfl_xor(v, o);
  return v;
}

__device__ __forceinline__ u16 bf16rne(float f) {
  unsigned u = __builtin_bit_cast(unsigned, f);
  return (u16)((u + 0x7fffu + ((u >> 16) & 1u)) >> 16);
}

// split fp32 into bf16 hi (RNE) + bf16 lo (RNE of remainder)
__device__ __forceinline__ void bsplit(float f, u16 &h, u16 &l) {
  unsigned u  = __builtin_bit_cast(unsigned, f);
  unsigned ur = u + 0x7fffu + ((u >> 16) & 1u);
  h = (u16)(ur >> 16);
  float fh = __builtin_bit_cast(float, ur & 0xffff0000u);
  float r  = f - fh;
  l = bf16rne(r);
}

__device__ __forceinline__ void bsplit8(float4 a, float4 b, uint4 &h, uint4 &l) {
  u16 h0,h1,h2,h3,h4,h5,h6,h7, l0,l1,l2,l3,l4,l5,l6,l7;
  bsplit(a.x,h0,l0); bsplit(a.y,h1,l1); bsplit(a.z,h2,l2); bsplit(a.w,h3,l3);
  bsplit(b.x,h4,l4); bsplit(b.y,h5,l5); bsplit(b.z,h6,l6); bsplit(b.w,h7,l7);
  h.x = (unsigned)h0 | ((unsigned)h1<<16); h.y = (unsigned)h2 | ((unsigned)h3<<16);
  h.z = (unsigned)h4 | ((unsigned)h5<<16); h.w = (unsigned)h6 | ((unsigned)h7<<16);
  l.x = (unsigned)l0 | ((unsigned)l1<<16); l.y = (unsigned)l2 | ((unsigned)l3<<16);
  l.z = (unsigned)l4 | ((unsigned)l5<<16); l.w = (unsigned)l6 | ((unsigned)l7<<16);
}

// 3-term split MFMA: (Ah+Al)(Bh+Bl) ~= AhBh + AhBl + AlBh
#define MFMA3(ACC)                                                                              \
  _Pragma("unroll") for (int i_ = 0; i_ < 2; ++i_)                                              \
  _Pragma("unroll") for (int j_ = 0; j_ < 2; ++j_) {                                            \
    ACC[i_][j_] = __builtin_amdgcn_mfma_f32_16x16x32_bf16(fAh[i_], fBh[j_], ACC[i_][j_],0,0,0); \
    ACC[i_][j_] = __builtin_amdgcn_mfma_f32_16x16x32_bf16(fAh[i_], fBl[j_], ACC[i_][j_],0,0,0); \
    ACC[i_][j_] = __builtin_amdgcn_mfma_f32_16x16x32_bf16(fAl[i_], fBh[j_], ACC[i_][j_],0,0,0); \
  }

// 2-term: A hi-only
#define MFMA2(ACC)                                                                              \
  _Pragma("unroll") for (int i_ = 0; i_ < 2; ++i_)                                              \
  _Pragma("unroll") for (int j_ = 0; j_ < 2; ++j_) {                                            \
    ACC[i_][j_] = __builtin_amdgcn_mfma_f32_16x16x32_bf16(fAh[i_], fBh[j_], ACC[i_][j_],0,0,0); \
    ACC[i_][j_] = __builtin_amdgcn_mfma_f32_16x16x32_bf16(fAh[i_], fBl[j_], ACC[i_][j_],0,0,0); \
  }

// ================= QKV: q/k/v = x @ W.T + b (fp32 in, split in staging) =================
// 64x64 tile, 8 waves = 2(kg) x 2(wr) x 2(wc), BK=32, dbuf LDS, 8 steps.
__global__ __launch_bounds__(512) void qkv_mfma(
    const float* __restrict__ x,
    const float* __restrict__ wq, const float* __restrict__ bq,
    const float* __restrict__ wk, const float* __restrict__ bk,
    const float* __restrict__ wv, const float* __restrict__ bv,
    u16* __restrict__ Qch,
    u16* __restrict__ Kch, u16* __restrict__ Kcl,
    u16* __restrict__ vTh, u16* __restrict__ vTl,
    float* __restrict__ qnpart, float* __restrict__ knpart,
    float* __restrict__ uh2a, float* __restrict__ vh2a)
{
  __shared__ __align__(16) u16 stage[2][20480];   // per buf: [2 kg][Ah|Al|Bh|Bl][64][40]
  float* fbuf = (float*)stage;                    // [2 kg][64][68]
  const int z = blockIdx.z;
  const float* W; const float* bias;
  if (z == 0)      { W = wq; bias = bq; }
  else if (z == 1) { W = wk; bias = bk; }
  else             { W = wv; bias = bv; }
  const int mBase = blockIdx.y << 6, nBase = blockIdx.x << 6;
  const int t = threadIdx.x, lane = t & 63, wave = t >> 6;
  const int kg = t >> 8, sub = t & 255;
  const int srow = sub >> 2, scol = (sub & 3) << 3;
  const int kgw = wave >> 2, wr = (wave >> 1) & 1, wc = wave & 1;

  const float* Ag = x + (size_t)(mBase + srow) * D_TOT + scol + kg * 256;
  const float* Bg = W + (size_t)(nBase + srow) * D_TOT + scol + kg * 256;

  const int sb = kg * 10240 + srow * 40 + scol;
  const int fa = kgw * 10240 + (wr * 32 + (lane & 15)) * 40 + ((lane >> 4) << 3);
  const int fb = kgw * 10240 + (wc * 32 + (lane & 15)) * 40 + ((lane >> 4) << 3);

  float4 a0 = *(const float4*)Ag, a1 = *(const float4*)(Ag + 4);
  float4 b0 = *(const float4*)Bg, b1 = *(const float4*)(Bg + 4);
  {
    uint4 hA,lA,hB,lB;
    bsplit8(a0,a1,hA,lA); bsplit8(b0,b1,hB,lB);
    *(uint4*)&stage[0][sb       ] = hA;
    *(uint4*)&stage[0][sb + 2560] = lA;
    *(uint4*)&stage[0][sb + 5120] = hB;
    *(uint4*)&stage[0][sb + 7680] = lB;
  }
  a0 = *(const float4*)(Ag + 32); a1 = *(const float4*)(Ag + 36);
  b0 = *(const float4*)(Bg + 32); b1 = *(const float4*)(Bg + 36);

  f32x4 zero = {0.f,0.f,0.f,0.f};
  f32x4 acc[2][2] = {{zero,zero},{zero,zero}};
#pragma unroll
  for (int r = 0; r < 8; ++r) {
    __syncthreads();
    const u16* bufr = stage[r & 1];
    bf16x8 fAh[2], fAl[2], fBh[2], fBl[2];
#pragma unroll
    for (int i = 0; i < 2; ++i) {
      fAh[i] = *(const bf16x8*)&bufr[fa        + i*640];
      fAl[i] = *(const bf16x8*)&bufr[fa + 2560 + i*640];
      fBh[i] = *(const bf16x8*)&bufr[fb + 5120 + i*640];
      fBl[i] = *(const bf16x8*)&bufr[fb + 7680 + i*640];
    }
    if (r + 1 < 8) {
      u16* bufw = stage[(r + 1) & 1];
      uint4 hA,lA,hB,lB;
      bsplit8(a0,a1,hA,lA); bsplit8(b0,b1,hB,lB);
      *(uint4*)&bufw[sb       ] = hA;
      *(uint4*)&bufw[sb + 2560] = lA;
      *(uint4*)&bufw[sb + 5120] = hB;
      *(uint4*)&bufw[sb + 7680] = lB;
      if (r + 2 < 8) {
        const int o = (r + 2) * 32;
        a0 = *(const float4*)(Ag + o); a1 = *(const float4*)(Ag + o + 4);
        b0 = *(const float4*)(Bg + o); b1 = *(const float4*)(Bg + o + 4);
      }
    }
    MFMA3(acc);
  }

  // --- cross-kg reduction (single round-trip) ---
  __syncthreads();
  {
    const int r0 = wr*32 + ((lane>>4)<<2);
    const int c0 = wc*32 + (lane&15);
#pragma unroll
    for (int i = 0; i < 2; ++i)
#pragma unroll
      for (int j = 0; j < 2; ++j)
#pragma unroll
        for (int g = 0; g < 4; ++g)
          fbuf[kgw*4352 + (r0 + i*16 + g)*68 + c0 + j*16] = acc[i][j][g];
  }
  __syncthreads();
  const int erow = wave << 3;
  float val[8];
  {
    const float b = bias[nBase + lane];
#pragma unroll
    for (int r = 0; r < 8; ++r)
      val[r] = fbuf[(erow+r)*68 + lane] + fbuf[4352 + (erow+r)*68 + lane] + b;
  }

  // --- epilogue ---
  if (z == 2) {
    u16 hh[8], ll[8];
#pragma unroll
    for (int r = 0; r < 8; ++r) bsplit(val[r], hh[r], ll[r]);
    const size_t off = (size_t)(nBase + lane) * S_LEN + mBase + erow;
    ushort4 p0{hh[0],hh[1],hh[2],hh[3]}, p1{hh[4],hh[5],hh[6],hh[7]};
    ushort4 q0{ll[0],ll[1],ll[2],ll[3]}, q1{ll[4],ll[5],ll[6],ll[7]};
    *(ushort4*)(vTh + off) = p0; *(ushort4*)(vTh + off + 4) = p1;
    *(ushort4*)(vTl + off) = q0; *(ushort4*)(vTl + off + 4) = q1;
  } else if (z == 1) {
    if (blockIdx.x < 7) {
#pragma unroll
      for (int r = 0; r < 8; ++r) {
        const int s = mBase + erow + r;
        u16 h,l; bsplit(val[r],h,l);
        Kch[(size_t)s*D_TOT + nBase + lane] = h;
        Kcl[(size_t)s*D_TOT + nBase + lane] = l;
        float p = wave_sum64(val[r]*val[r]);
        if (lane == 0) knpart[s*8 + blockIdx.x] = p;
      }
    } else {
#pragma unroll
      for (int r = 0; r < 8; ++r) {
        const int s = mBase + erow + r;
        float n2 = wave_sum64(val[r]*val[r]);
        float nn = sqrtf(n2);
        float n  = fmaxf(nn, 1e-5f);
        float e2n = __expf(2.f*n);
        float th  = 1.f - 2.f*frcp(e2n + 1.f);
        float rn  = frcp(n);
        float pn  = th * nn * rn;
        float scale = fminf(0.999f * frcp(fmaxf(pn, 1e-5f)), 1.f);
        float u = th * rn * scale * val[r];
        float un = pn * scale;
        u16 h,l; bsplit(u,h,l);
        Kch[(size_t)s*D_TOT + nBase + lane] = h;
        Kcl[(size_t)s*D_TOT + nBase + lane] = l;
        if (lane == 0) vh2a[s] = un*un;
      }
    }
  } else {
    if (blockIdx.x < 7) {
#pragma unroll
      for (int r = 0; r < 8; ++r) {
        const int s = mBase + erow + r;
        Qch[(size_t)s*D_TOT + nBase + lane] = bf16rne(val[r]);
        float p = wave_sum64(val[r]*val[r]);
        if (lane == 0) qnpart[s*8 + blockIdx.x] = p;
      }
    } else {
#pragma unroll
      for (int r = 0; r < 8; ++r) {
        const int s = mBase + erow + r;
        float n2 = wave_sum64(val[r]*val[r]);
        float nn = sqrtf(n2);
        float n  = fmaxf(nn, 1e-5f);
        float e2n = __expf(2.f*n);
        float th  = 1.f - 2.f*frcp(e2n + 1.f);
        float rn  = frcp(n);
        float pn  = th * nn * rn;
        float scale = fminf(0.999f * frcp(fmaxf(pn, 1e-5f)), 1.f);
        float u = th * rn * scale * val[r];
        float un = pn * scale;
        Qch[(size_t)s*D_TOT + nBase + lane] = bf16rne(u);
        if (lane == 0) uh2a[s] = un*un;
      }
    }
  }
}

// ================= scores + exp + partial rowsums (Q hi-only, MFMA2) =================
__global__ __launch_bounds__(512) void score_mfma(
    const u16* __restrict__ Qch,
    const u16* __restrict__ Kch, const u16* __restrict__ Kcl,
    const float* __restrict__ qnpart, const float* __restrict__ knpart,
    const float* __restrict__ uh2a, const float* __restrict__ vh2a,
    const float* __restrict__ alpha_u,
    u16* __restrict__ Eh, float* __restrict__ rowpart)
{
  // stage: 2 bufs x [2 kg][Ah|Bh|Bl][64][40] u16 = 61440 B; fbuf overlay: 17408 f = 69632 B
  __shared__ __align__(16) char shm_[69632];
  __shared__ float rowscal[256];    // qn[64] kn[64] u2[64] v2[64]
  u16* stg = (u16*)shm_;
  float* fbuf = (float*)shm_;
  const int t = threadIdx.x, lane = t & 63, wave = t >> 6;
  const int mBase = blockIdx.y << 6, nBase = blockIdx.x << 6;
  if (t < 64) {
    float s_ = 0.f;
#pragma unroll
    for (int c = 0; c < 7; ++c) s_ += qnpart[(mBase+t)*8 + c];
    rowscal[t] = s_;
  } else if (t < 128) {
    float s_ = 0.f;
#pragma unroll
    for (int c = 0; c < 7; ++c) s_ += knpart[(nBase+t-64)*8 + c];
    rowscal[t] = s_;
  } else if (t < 192) rowscal[t] = uh2a[mBase + t - 128];
  else if (t < 256)   rowscal[t] = vh2a[nBase + t - 192];

  const int kg = t >> 8, sub = t & 255;
  const int srow = sub >> 2, scol = (sub & 3) << 3;
  const int kgw = wave >> 2, wr = (wave >> 1) & 1, wc = wave & 1;
  const u16* Agh = Qch + (size_t)(mBase+srow)*D_TOT + scol;
  const u16* Bgh = Kch + (size_t)(nBase+srow)*D_TOT + scol;
  const u16* Bgl = Kcl + (size_t)(nBase+srow)*D_TOT + scol;

  const int sb  = kg * 7680 + srow * 40 + scol;
  const int fa  = kgw * 7680 + (wr * 32 + (lane & 15)) * 40 + ((lane >> 4) << 3);
  const int fbh = kgw * 7680 + 2560 + (wc * 32 + (lane & 15)) * 40 + ((lane >> 4) << 3);

  int kb = kg * 224;
  uint4 rAh = *(const uint4*)(Agh + kb);
  uint4 rBh = *(const uint4*)(Bgh + kb), rBl = *(const uint4*)(Bgl + kb);
  *(uint4*)&stg[sb       ] = rAh;
  *(uint4*)&stg[sb + 2560] = rBh;
  *(uint4*)&stg[sb + 5120] = rBl;
  kb = kg * 224 + 32;
  rAh = *(const uint4*)(Agh + kb);
  rBh = *(const uint4*)(Bgh + kb); rBl = *(const uint4*)(Bgl + kb);

  f32x4 zero = {0.f,0.f,0.f,0.f};
  f32x4 accE[2][2] = {{zero,zero},{zero,zero}};
  f32x4 accH[2][2] = {{zero,zero},{zero,zero}};
#pragma unroll
  for (int r = 0; r < 8; ++r) {
    __syncthreads();
    const u16* bufr = stg + (r & 1) * 15360;
    bf16x8 fAh[2], fBh[2], fBl[2];
#pragma unroll
    for (int i = 0; i < 2; ++i) {
      fAh[i] = *(const bf16x8*)&bufr[fa         + i*640];
      fBh[i] = *(const bf16x8*)&bufr[fbh        + i*640];
      fBl[i] = *(const bf16x8*)&bufr[fbh + 2560 + i*640];
    }
    if (r + 1 < 8) {
      u16* bufw = stg + ((r + 1) & 1) * 15360;
      *(uint4*)&bufw[sb       ] = rAh;
      *(uint4*)&bufw[sb + 2560] = rBh;
      *(uint4*)&bufw[sb + 5120] = rBl;
      if (r + 2 < 8) {
        const int o = (r + 2 < 7) ? (kg*224 + (r+2)*32) : (448 + kg*32);
        rAh = *(const uint4*)(Agh + o);
        rBh = *(const uint4*)(Bgh + o); rBl = *(const uint4*)(Bgl + o);
      }
    }
    if (r < 7) { MFMA2(accE) } else { MFMA2(accH) }
  }

  // --- single round-trip cross-kg reduction of E and H ---
  __syncthreads();
  {
    const int r0 = wr*32 + ((lane>>4)<<2);
    const int c0 = wc*32 + (lane&15);
#pragma unroll
    for (int i = 0; i < 2; ++i)
#pragma unroll
      for (int j = 0; j < 2; ++j)
#pragma unroll
        for (int g = 0; g < 4; ++g) {
          fbuf[       kgw*4352 + (r0 + i*16 + g)*68 + c0 + j*16] = accE[i][j][g];
          fbuf[8704 + kgw*4352 + (r0 + i*16 + g)*68 + c0 + j*16] = accH[i][j][g];
        }
  }
  __syncthreads();
  const int erow = wave << 3;
  float eE[8], eH[8];
#pragma unroll
  for (int r = 0; r < 8; ++r) {
    eE[r] = fbuf[(erow+r)*68 + lane] + fbuf[4352 + (erow+r)*68 + lane];
    eH[r] = fbuf[8704 + (erow+r)*68 + lane] + fbuf[8704 + 4352 + (erow+r)*68 + lane];
  }

  // --- transcendental epilogue ---
  const float alpha = __logf(1.f + __expf(alpha_u[0]));
  const float inv_s = 0.04419417382415922f;   // 1/sqrt(512)
  const float knl = rowscal[64 + lane], v2 = rowscal[192 + lane];
#pragma unroll
  for (int r = 0; r < 8; ++r) {
    const int s = mBase + erow + r;
    const float qns = rowscal[erow + r], u2 = rowscal[128 + erow + r];
    float de   = qns + knl - 2.f * eE[r];
    float dH   = eH[r];
    float Ac   = 1.f - 2.f*dH + v2;
    float Bc   = 1.f - u2;
    float num2 = Ac*Ac*u2 + Bc*Bc*v2 - 2.f*Ac*Bc*dH;
    float den  = fmaxf(1.f - 2.f*dH + u2*v2, 1e-5f);
    float frac = sqrtf(fmaxf(num2, 0.f)) * frcp(den);
    float nrm  = fminf(frac, 0.999f);
    float dh_  = __logf((1.f + nrm) * frcp(1.f - nrm));   // = 2*atanh(nrm)
    float dist = de + alpha * dh_ * dh_;
    float lg   = fminf(fmaxf(-dist * inv_s, -50.f), 0.f);
    float e    = __expf(lg);
    Eh[(size_t)s*S_LEN + nBase + lane] = bf16rne(e);
    float rs = wave_sum64(e);
    if (lane == 0) rowpart[s*16 + blockIdx.x] = rs;
  }
}

// ================= attn @ V (E hi-only) =================
// 32x64 tile, 8 waves = 4(kg) x 2(wc), K=1024, dbuf, 8 steps.
__global__ __launch_bounds__(512) void av_mfma(
    const u16* __restrict__ Eh,
    const u16* __restrict__ vTh, const u16* __restrict__ vTl,
    const float* __restrict__ rowpart,
    u16* __restrict__ out1h, u16* __restrict__ out1l)
{
  __shared__ __align__(16) u16 stage[2][25600];  // per buf per kg: [Ah 1280][Bh 2560][Bl 2560]
  __shared__ float rinvl[32];
  float* fbuf = (float*)stage;                   // [4 kg][32][68]
  const int t = threadIdx.x, lane = t & 63, wave = t >> 6;
  const int mBase = blockIdx.y << 5, nBase = blockIdx.x << 6;
  if (t < 32) {
    float s_ = 0.f;
#pragma unroll
    for (int c = 0; c < 16; ++c) s_ += rowpart[(mBase+t)*16 + c];
    rinvl[t] = 1.f / s_;
  }
  const int kg = t >> 7, sub = t & 127;
  const int arow = sub >> 2, acol = (sub & 3) << 3;
  const int brow0 = sub >> 2, bcol0 = (sub & 3) << 3;
  const int brow1 = (sub + 128) >> 2, bcol1 = ((sub + 128) & 3) << 3;
  const int kgw = wave >> 1, wc = wave & 1;

  const u16* Ag  = Eh  + (size_t)(mBase+arow)*S_LEN + acol + kg*256;
  const u16* B0h = vTh + (size_t)(nBase+brow0)*S_LEN + bcol0 + kg*256;
  const u16* B0l = vTl + (size_t)(nBase+brow0)*S_LEN + bcol0 + kg*256;
  const u16* B1h = vTh + (size_t)(nBase+brow1)*S_LEN + bcol1 + kg*256;
  const u16* B1l = vTl + (size_t)(nBase+brow1)*S_LEN + bcol1 + kg*256;

  const int sA  = kg*6400 + arow*40 + acol;
  const int sB0 = kg*6400 + 1280 + brow0*40 + bcol0;
  const int sB1 = kg*6400 + 1280 + brow1*40 + bcol1;
  const int fa  = kgw*6400 + (lane&15)*40 + ((lane>>4)<<3);
  const int fbh = kgw*6400 + 1280 + (wc*32 + (lane&15))*40 + ((lane>>4)<<3);

  uint4 rA = *(const uint4*)Ag;
  uint4 rb0h = *(const uint4*)B0h, rb0l = *(const uint4*)B0l;
  uint4 rb1h = *(const uint4*)B1h, rb1l = *(const uint4*)B1l;
  *(uint4*)&stage[0][sA        ] = rA;
  *(uint4*)&stage[0][sB0       ] = rb0h; *(uint4*)&stage[0][sB0 + 2560] = rb0l;
  *(uint4*)&stage[0][sB1       ] = rb1h; *(uint4*)&stage[0][sB1 + 2560] = rb1l;
  rA = *(const uint4*)(Ag + 32);
  rb0h = *(const uint4*)(B0h + 32); rb0l = *(const uint4*)(B0l + 32);
  rb1h = *(const uint4*)(B1h + 32); rb1l = *(const uint4*)(B1l + 32);

  f32x4 zero = {0.f,0.f,0.f,0.f};
  f32x4 acc[2][2] = {{zero,zero},{zero,zero}};
#pragma unroll
  for (int r = 0; r < 8; ++r) {
    __syncthreads();
    const u16* bufr = stage[r & 1];
    bf16x8 fAh[2], fBh[2], fBl[2];
#pragma unroll
    for (int i = 0; i < 2; ++i) {
      fAh[i] = *(const bf16x8*)&bufr[fa         + i*640];
      fBh[i] = *(const bf16x8*)&bufr[fbh        + i*640];
      fBl[i] = *(const bf16x8*)&bufr[fbh + 2560 + i*640];
    }
    if (r + 1 < 8) {
      u16* bufw = stage[(r + 1) & 1];
      *(uint4*)&bufw[sA        ] = rA;
      *(uint4*)&bufw[sB0       ] = rb0h; *(uint4*)&bufw[sB0 + 2560] = rb0l;
      *(uint4*)&bufw[sB1       ] = rb1h; *(uint4*)&bufw[sB1 + 2560] = rb1l;
      if (r + 2 < 8) {
        const int o = (r + 2) * 32;
        rA = *(const uint4*)(Ag + o);
        rb0h = *(const uint4*)(B0h + o); rb0l = *(const uint4*)(B0l + o);
        rb1h = *(const uint4*)(B1h + o); rb1l = *(const uint4*)(B1l + o);
      }
    }
    MFMA2(acc);
  }

  __syncthreads();
  {
    const int r0 = (lane>>4)<<2;
    const int c0 = wc*32 + (lane&15);
#pragma unroll
    for (int i = 0; i < 2; ++i)
#pragma unroll
      for (int j = 0; j < 2; ++j)
#pragma unroll
        for (int g = 0; g < 4; ++g)
          fbuf[kgw*2176 + (r0 + i*16 + g)*68 + c0 + j*16] = acc[i][j][g];
  }
  __syncthreads();
  const int erow = wave << 2;
#pragma unroll
  for (int r = 0; r < 4; ++r) {
    const int row = erow + r;
    float e = fbuf[row*68 + lane] + fbuf[2176 + row*68 + lane]
            + fbuf[4352 + row*68 + lane] + fbuf[6528 + row*68 + lane];
    float v_ = e * rinvl[row];
    u16 h,l; bsplit(v_,h,l);
    const int s = mBase + row;
    out1h[(size_t)s*D_TOT + nBase + lane] = h;
    out1l[(size_t)s*D_TOT + nBase + lane] = l;
  }
}

// ================= final: out = out1 @ wo.T + bo (wo fp32, split in staging) =================
__global__ __launch_bounds__(512) void final_mfma(
    const u16* __restrict__ out1h, const u16* __restrict__ out1l,
    const float* __restrict__ wo, const float* __restrict__ bo,
    float* __restrict__ out)
{
  __shared__ __align__(16) u16 stage[2][30720];  // per buf per kg: [Ah 1280][Al 1280][Bh 2560][Bl 2560]
  float* fbuf = (float*)stage;
  const int t = threadIdx.x, lane = t & 63, wave = t >> 6;
  const int mBase = blockIdx.y << 5, nBase = blockIdx.x << 6;
  const int kg = t >> 7, sub = t & 127;
  const int arow = sub >> 2, acol = (sub & 3) << 3;
  const int brow0 = sub >> 2, bcol0 = (sub & 3) << 3;
  const int brow1 = (sub + 128) >> 2, bcol1 = ((sub + 128) & 3) << 3;
  const int kgw = wave >> 1, wc = wave & 1;

  const u16* Agh = out1h + (size_t)(mBase+arow)*D_TOT + acol + kg*128;
  const u16* Agl = out1l + (size_t)(mBase+arow)*D_TOT + acol + kg*128;
  const float* B0 = wo + (size_t)(nBase+brow0)*D_TOT + bcol0 + kg*128;
  const float* B1 = wo + (size_t)(nBase+brow1)*D_TOT + bcol1 + kg*128;

  const int sA  = kg*7680 + arow*40 + acol;
  const int sB0 = kg*7680 + 2560 + brow0*40 + bcol0;
  const int sB1 = kg*7680 + 2560 + brow1*40 + bcol1;
  const int fa  = kgw*7680 + (lane&15)*40 + ((lane>>4)<<3);
  const int fbh = kgw*7680 + 2560 + (wc*32 + (lane&15))*40 + ((lane>>4)<<3);

  uint4 rah = *(const uint4*)Agh, ral = *(const uint4*)Agl;
  float4 b00 = *(const float4*)B0, b01 = *(const float4*)(B0 + 4);
  float4 b10 = *(const float4*)B1, b11 = *(const float4*)(B1 + 4);
  {
    uint4 bh0,bl0,bh1,bl1;
    bsplit8(b00,b01,bh0,bl0); bsplit8(b10,b11,bh1,bl1);
    *(uint4*)&stage[0][sA        ] = rah; *(uint4*)&stage[0][sA  + 1280] = ral;
    *(uint4*)&stage[0][sB0       ] = bh0; *(uint4*)&stage[0][sB0 + 2560] = bl0;
    *(uint4*)&stage[0][sB1       ] = bh1; *(uint4*)&stage[0][sB1 + 2560] = bl1;
  }
  rah = *(const uint4*)(Agh + 32); ral = *(const uint4*)(Agl + 32);
  b00 = *(const float4*)(B0 + 32); b01 = *(const float4*)(B0 + 36);
  b10 = *(const float4*)(B1 + 32); b11 = *(const float4*)(B1 + 36);

  f32x4 zero = {0.f,0.f,0.f,0.f};
  f32x4 acc[2][2] = {{zero,zero},{zero,zero}};
#pragma unroll
  for (int r = 0; r < 4; ++r) {
    __syncthreads();
    const u16* bufr = stage[r & 1];
    bf16x8 fAh[2], fAl[2], fBh[2], fBl[2];
#pragma unroll
    for (int i = 0; i < 2; ++i) {
      fAh[i] = *(const bf16x8*)&bufr[fa         + i*640];
      fAl[i] = *(const bf16x8*)&bufr[fa + 1280  + i*640];
      fBh[i] = *(const bf16x8*)&bufr[fbh        + i*640];
      fBl[i] = *(const bf16x8*)&bufr[fbh + 2560 + i*640];
    }
    if (r + 1 < 4) {
      u16* bufw = stage[(r + 1) & 1];
      uint4 bh0,bl0,bh1,bl1;
      bsplit8(b00,b01,bh0,bl0); bsplit8(b10,b11,bh1,bl1);
      *(uint4*)&bufw[sA        ] = rah; *(uint4*)&bufw[sA  + 1280] = ral;
      *(uint4*)&bufw[sB0       ] = bh0; *(uint4*)&bufw[sB0 + 2560] = bl0;
      *(uint4*)&bufw[sB1       ] = bh1; *(uint4*)&bufw[sB1 + 2560] = bl1;
      if (r + 2 < 4) {
        const int o = (r + 2) * 32;
        rah = *(const uint4*)(Agh + o); ral = *(const uint4*)(Agl + o);
        b00 = *(const float4*)(B0 + o); b01 = *(const float4*)(B0 + o + 4);
        b10 = *(const float4*)(B1 + o); b11 = *(const float4*)(B1 + o + 4);
      }
    }
    MFMA3(acc);
  }

  __syncthreads();
  {
    const int r0 = (lane>>4)<<2;
    const int c0 = wc*32 + (lane&15);
#pragma unroll
    for (int i = 0; i < 2; ++i)
#pragma unroll
      for (int j = 0; j < 2; ++j)
#pragma unroll
        for (int g = 0; g < 4; ++g)
          fbuf[kgw*2176 + (r0 + i*16 + g)*68 + c0 + j*16] = acc[i][j][g];
  }
  __syncthreads();
  const int erow = wave << 2;
  const float b = bo[nBase + lane];
#pragma unroll
  for (int r = 0; r < 4; ++r) {
    const int row = erow + r;
    float e = fbuf[row*68 + lane] + fbuf[2176 + row*68 + lane]
            + fbuf[4352 + row*68 + lane] + fbuf[6528 + row*68 + lane];
    out[(size_t)(mBase+row)*D_TOT + nBase + lane] = e + b;
  }
}

extern "C" void kernel_launch(void* const* d_in, const int* in_sizes, int n_in,
                              void* d_out, int out_size, void* d_ws, size_t ws_size,
                              hipStream_t stream)
{
  const float* x   = (const float*)d_in[0];
  const float* wq  = (const float*)d_in[1];
  const float* bq  = (const float*)d_in[2];
  const float* wk  = (const float*)d_in[3];
  const float* bk  = (const float*)d_in[4];
  const float* wv  = (const float*)d_in[5];
  const float* bv  = (const float*)d_in[6];
  const float* wo  = (const float*)d_in[7];
  const float* bo  = (const float*)d_in[8];
  const float* alpha_u = (const float*)d_in[9];
  float* out = (float*)d_out;

  u16* U = (u16*)d_ws;
  u16* Qch   = U + 0;
  u16* Kch   = U + 524288;
  u16* Kcl   = U + 1048576;
  u16* vTh   = U + 1572864;
  u16* vTl   = U + 2097152;
  u16* Eh    = U + 2621440;   // 1048576
  u16* out1h = U + 3670016;
  u16* out1l = U + 4194304;
  float* F = (float*)(U + 4718592);
  float* qnpart  = F;          // [1024][8]
  float* knpart  = F + 8192;
  float* uh2a    = F + 16384;
  float* vh2a    = F + 17408;
  float* rowpart = F + 18432;  // [1024][16]

  qkv_mfma<<<dim3(8,16,3), 512, 0, stream>>>(x, wq,bq, wk,bk, wv,bv,
      Qch, Kch, Kcl, vTh, vTl, qnpart, knpart, uh2a, vh2a);
  score_mfma<<<dim3(16,16), 512, 0, stream>>>(Qch, Kch, Kcl,
      qnpart, knpart, uh2a, vh2a, alpha_u, Eh, rowpart);
  av_mfma<<<dim3(8,32), 512, 0, stream>>>(Eh, vTh, vTl, rowpart, out1h, out1l);
  final_mfma<<<dim3(8,32), 512, 0, stream>>>(out1h, out1l, wo, bo, out);
}